// Round 1
// baseline (2922.378 us; speedup 1.0000x reference)
//
#include <hip/hip_runtime.h>
#include <hip/hip_bf16.h>
#include <math.h>

#define B_   16384
#define S_   4
#define E_   1152
#define D_   192
#define H_   4
#define DH_  48
#define FF_  768
#define NL_  2
#define MTOK (B_ * S_)   // 65536 tokens

__device__ __forceinline__ float gelu_f(float x) {
  // exact erf GELU (matches jax approximate=False / torch GELU default)
  return 0.5f * x * (1.0f + erff(x * 0.70710678118654752f));
}

// ---------------------------------------------------------------------------
// LN stats over E=1152 (one block per token)
// ---------------------------------------------------------------------------
__global__ __launch_bounds__(256) void stats_e_kernel(const float* __restrict__ emb,
                                                      float* __restrict__ st) {
  int m = blockIdx.x;
  const float* row = emb + (size_t)m * E_;
  float sum = 0.f, sq = 0.f;
  for (int idx = threadIdx.x; idx < E_; idx += 256) {
    float v = row[idx];
    sum += v; sq += v * v;
  }
  #pragma unroll
  for (int off = 1; off < 64; off <<= 1) {
    sum += __shfl_xor(sum, off);
    sq  += __shfl_xor(sq, off);
  }
  __shared__ float ls[4], lq[4];
  int wid = threadIdx.x >> 6;
  if ((threadIdx.x & 63) == 0) { ls[wid] = sum; lq[wid] = sq; }
  __syncthreads();
  if (threadIdx.x == 0) {
    float s = ls[0] + ls[1] + ls[2] + ls[3];
    float q = lq[0] + lq[1] + lq[2] + lq[3];
    float mean = s / (float)E_;
    float var  = q / (float)E_ - mean * mean;
    st[2 * m]     = mean;
    st[2 * m + 1] = rsqrtf(var + 1e-5f);
  }
}

// ---------------------------------------------------------------------------
// LN stats over D=192 (one wave per token, 4 waves/block)
// ---------------------------------------------------------------------------
__global__ __launch_bounds__(256) void stats_d_kernel(const float* __restrict__ x,
                                                      float* __restrict__ st) {
  int m = blockIdx.x * 4 + (threadIdx.x >> 6);
  int lane = threadIdx.x & 63;
  const float* row = x + (size_t)m * D_;
  float v0 = row[lane], v1 = row[lane + 64], v2 = row[lane + 128];
  float sum = v0 + v1 + v2;
  #pragma unroll
  for (int off = 1; off < 64; off <<= 1) sum += __shfl_xor(sum, off);
  float mean = sum / (float)D_;
  float d0 = v0 - mean, d1 = v1 - mean, d2 = v2 - mean;
  float vs = d0 * d0 + d1 * d1 + d2 * d2;
  #pragma unroll
  for (int off = 1; off < 64; off <<= 1) vs += __shfl_xor(vs, off);
  if (lane == 0) {
    st[2 * m]     = mean;
    st[2 * m + 1] = rsqrtf(vs / (float)D_ + 1e-5f);
  }
}

// ---------------------------------------------------------------------------
// fp32 GEMM: C[M,N] = epilogue(Aln[M,K] @ W[N,K]^T + bias)
//   LN_A: apply (a - mean)*rstd*g + b per A row during staging (stats precomputed)
//   EPI: 0 = bias; 1 = bias+GELU; 2 = bias + residual (res[M,N]); 3 = bias+GELU+posenc
// 64x64x16 tiles, 256 threads, 4x4 microtile. M,N % 64 == 0, K % 16 == 0.
// ---------------------------------------------------------------------------
template <bool LN_A, int EPI>
__global__ __launch_bounds__(256) void gemm_f32(
    const float* __restrict__ A, const float* __restrict__ W,
    const float* __restrict__ bias, const float* __restrict__ stats,
    const float* __restrict__ lng, const float* __restrict__ lnb,
    const float* __restrict__ res, float* __restrict__ C,
    int M, int N, int K) {
  __shared__ float As[16][68];   // [k][m], padded stride 68: staging writes 2-way only
  __shared__ float Bs[16][68];   // [k][n]
  const int tid = threadIdx.x;
  const int m0 = blockIdx.x * 64;
  const int n0 = blockIdx.y * 64;
  const int tx = tid & 15, ty = tid >> 4;
  const int lr = tid >> 2;          // 0..63: row within tile for staging
  const int lk = (tid & 3) << 2;    // 0,4,8,12: k offset for staging
  float acc[4][4] = {};
  float sm = 0.f, srs = 0.f;
  if constexpr (LN_A) {
    sm  = stats[2 * (m0 + lr)];
    srs = stats[2 * (m0 + lr) + 1];
  }
  const float* Arow = A + (size_t)(m0 + lr) * K;
  const float* Wrow = W + (size_t)(n0 + lr) * K;
  for (int k0 = 0; k0 < K; k0 += 16) {
    float4 av = *(const float4*)(Arow + k0 + lk);
    float4 wv = *(const float4*)(Wrow + k0 + lk);
    if constexpr (LN_A) {
      float4 g  = *(const float4*)(lng + k0 + lk);
      float4 bb = *(const float4*)(lnb + k0 + lk);
      av.x = (av.x - sm) * srs * g.x + bb.x;
      av.y = (av.y - sm) * srs * g.y + bb.y;
      av.z = (av.z - sm) * srs * g.z + bb.z;
      av.w = (av.w - sm) * srs * g.w + bb.w;
    }
    __syncthreads();
    As[lk + 0][lr] = av.x; As[lk + 1][lr] = av.y;
    As[lk + 2][lr] = av.z; As[lk + 3][lr] = av.w;
    Bs[lk + 0][lr] = wv.x; Bs[lk + 1][lr] = wv.y;
    Bs[lk + 2][lr] = wv.z; Bs[lk + 3][lr] = wv.w;
    __syncthreads();
    #pragma unroll
    for (int kk = 0; kk < 16; ++kk) {
      float4 a = *(const float4*)&As[kk][ty * 4];
      float4 b = *(const float4*)&Bs[kk][tx * 4];
      acc[0][0] += a.x * b.x; acc[0][1] += a.x * b.y; acc[0][2] += a.x * b.z; acc[0][3] += a.x * b.w;
      acc[1][0] += a.y * b.x; acc[1][1] += a.y * b.y; acc[1][2] += a.y * b.z; acc[1][3] += a.y * b.w;
      acc[2][0] += a.z * b.x; acc[2][1] += a.z * b.y; acc[2][2] += a.z * b.z; acc[2][3] += a.z * b.w;
      acc[3][0] += a.w * b.x; acc[3][1] += a.w * b.y; acc[3][2] += a.w * b.z; acc[3][3] += a.w * b.w;
    }
  }
  float4 bv = *(const float4*)(bias + n0 + tx * 4);
  #pragma unroll
  for (int i = 0; i < 4; ++i) {
    int m = m0 + ty * 4 + i;
    float v0 = acc[i][0] + bv.x, v1 = acc[i][1] + bv.y;
    float v2 = acc[i][2] + bv.z, v3 = acc[i][3] + bv.w;
    if constexpr (EPI == 1 || EPI == 3) {
      v0 = gelu_f(v0); v1 = gelu_f(v1); v2 = gelu_f(v2); v3 = gelu_f(v3);
    }
    if constexpr (EPI == 3) {
      // sinusoidal pos-enc: pe[s][2j] = sin(s*div_j), pe[s][2j+1] = cos(s*div_j),
      // div_j = exp(2j * (-ln(10000)/D)).  nb is even by construction.
      float fs = (float)(m & 3);
      int nb = n0 + tx * 4;
      float ang0 = fs * expf((float)nb       * (-0.047970522770709292f));
      float ang1 = fs * expf((float)(nb + 2) * (-0.047970522770709292f));
      v0 += sinf(ang0); v1 += cosf(ang0);
      v2 += sinf(ang1); v3 += cosf(ang1);
    }
    if constexpr (EPI == 2) {
      float4 rv = *(const float4*)(res + (size_t)m * N + n0 + tx * 4);
      v0 += rv.x; v1 += rv.y; v2 += rv.z; v3 += rv.w;
    }
    float4 ov; ov.x = v0; ov.y = v1; ov.z = v2; ov.w = v3;
    *(float4*)(C + (size_t)m * N + n0 + tx * 4) = ov;
  }
}

// ---------------------------------------------------------------------------
// Attention: S=4, H=4, DH=48. 4 samples per block, one wave per sample.
// qkv row layout per token: [q(192) | k(192) | v(192)], q[h*48+dh].
// ---------------------------------------------------------------------------
__global__ __launch_bounds__(256) void attn_kernel(const float* __restrict__ qkv,
                                                   float* __restrict__ o) {
  __shared__ float sq[4][4][576];       // [sample][s][qkv-col]
  __shared__ float sp[4][4][4][4];      // [sample][h][i][j] softmax probs
  int tid = threadIdx.x;
  int b0 = blockIdx.x * 4;
  const float4* src = (const float4*)(qkv + (size_t)b0 * 4 * 576);
  float4* dst = (float4*)&sq[0][0][0];
  #pragma unroll
  for (int t = 0; t < 9; ++t) dst[tid + t * 256] = src[tid + t * 256];  // 2304 float4
  __syncthreads();
  int sg = tid >> 6;
  int lane = tid & 63;
  int h = lane >> 4, i = (lane >> 2) & 3, j = lane & 3;
  const float* qp = &sq[sg][i][h * 48];
  const float* kp = &sq[sg][j][192 + h * 48];
  float s = 0.f;
  #pragma unroll
  for (int d = 0; d < 48; ++d) s += qp[d] * kp[d];
  s *= 0.14433756729740643f;  // 1/sqrt(48)
  float mx = fmaxf(s, __shfl_xor(s, 1));
  mx = fmaxf(mx, __shfl_xor(mx, 2));
  float e = expf(s - mx);
  float sum = e + __shfl_xor(e, 1);
  sum += __shfl_xor(sum, 2);
  sp[sg][h][i][j] = e / sum;
  __syncthreads();
  #pragma unroll
  for (int ii = 0; ii < 4; ++ii) {
    #pragma unroll
    for (int cc = 0; cc < 3; ++cc) {
      int c = lane + cc * 64;
      int hh = c / 48;
      float acc = 0.f;
      #pragma unroll
      for (int jj = 0; jj < 4; ++jj)
        acc += sp[sg][hh][ii][jj] * sq[sg][jj][384 + c];
      o[((size_t)(b0 + sg) * 4 + ii) * D_ + c] = acc;
    }
  }
}

// ---------------------------------------------------------------------------
// mean-pool over S=4 + head LN (one wave per sample)
// ---------------------------------------------------------------------------
__global__ __launch_bounds__(256) void pool_ln_kernel(const float* __restrict__ x,
                                                      const float* __restrict__ g,
                                                      const float* __restrict__ b,
                                                      float* __restrict__ hout) {
  int bi = blockIdx.x * 4 + (threadIdx.x >> 6);
  int lane = threadIdx.x & 63;
  const float* row = x + (size_t)bi * 4 * D_;
  float vals[3];
  float sum = 0.f;
  #pragma unroll
  for (int cc = 0; cc < 3; ++cc) {
    int d = lane + cc * 64;
    float v = 0.25f * (row[d] + row[D_ + d] + row[2 * D_ + d] + row[3 * D_ + d]);
    vals[cc] = v; sum += v;
  }
  #pragma unroll
  for (int off = 1; off < 64; off <<= 1) sum += __shfl_xor(sum, off);
  float mean = sum / (float)D_;
  float vs = 0.f;
  #pragma unroll
  for (int cc = 0; cc < 3; ++cc) { float d0 = vals[cc] - mean; vs += d0 * d0; }
  #pragma unroll
  for (int off = 1; off < 64; off <<= 1) vs += __shfl_xor(vs, off);
  float rstd = rsqrtf(vs / (float)D_ + 1e-5f);
  #pragma unroll
  for (int cc = 0; cc < 3; ++cc) {
    int d = lane + cc * 64;
    hout[(size_t)bi * D_ + d] = (vals[cc] - mean) * rstd * g[d] + b[d];
  }
}

// ---------------------------------------------------------------------------
// final: out[b] = h2[b,:64] . h3_w + h3_b  (one wave per sample)
// ---------------------------------------------------------------------------
__global__ __launch_bounds__(256) void head_final_kernel(const float* __restrict__ h2,
                                                         const float* __restrict__ w,
                                                         const float* __restrict__ b,
                                                         float* __restrict__ out) {
  int bi = blockIdx.x * 4 + (threadIdx.x >> 6);
  int lane = threadIdx.x & 63;
  float v = h2[(size_t)bi * 64 + lane] * w[lane];
  #pragma unroll
  for (int off = 1; off < 64; off <<= 1) v += __shfl_xor(v, off);
  if (lane == 0) out[bi] = v + b[0];
}

// ---------------------------------------------------------------------------
extern "C" void kernel_launch(void* const* d_in, const int* in_sizes, int n_in,
                              void* d_out, int out_size, void* d_ws, size_t ws_size,
                              hipStream_t stream) {
  (void)in_sizes; (void)n_in; (void)out_size; (void)ws_size;
  const float* emb       = (const float*)d_in[0];
  const float* in_ln_w   = (const float*)d_in[1];
  const float* in_ln_b   = (const float*)d_in[2];
  const float* in_proj_w = (const float*)d_in[3];
  const float* in_proj_b = (const float*)d_in[4];
  const float* qkv_w     = (const float*)d_in[5];
  const float* qkv_b     = (const float*)d_in[6];
  const float* aow       = (const float*)d_in[7];
  const float* aob       = (const float*)d_in[8];
  const float* ln1w      = (const float*)d_in[9];
  const float* ln1b      = (const float*)d_in[10];
  const float* ln2w      = (const float*)d_in[11];
  const float* ln2b      = (const float*)d_in[12];
  const float* ff1w      = (const float*)d_in[13];
  const float* ff1b      = (const float*)d_in[14];
  const float* ff2w      = (const float*)d_in[15];
  const float* ff2b      = (const float*)d_in[16];
  const float* hlnw      = (const float*)d_in[17];
  const float* hlnb      = (const float*)d_in[18];
  const float* h1w       = (const float*)d_in[19];
  const float* h1b       = (const float*)d_in[20];
  const float* h2w       = (const float*)d_in[21];
  const float* h2b       = (const float*)d_in[22];
  const float* h3w       = (const float*)d_in[23];
  const float* h3b       = (const float*)d_in[24];
  float* out = (float*)d_out;

  // workspace layout (fp32 elements); residual adds are in-place on x.
  float* ws = (float*)d_ws;
  size_t off = 0;
  float* x   = ws + off; off += (size_t)MTOK * D_;     // 65536x192
  float* qf  = ws + off; off += (size_t)MTOK * FF_;    // shared: qkv (576 cols) / ff (768 cols)
  float* o   = qf + (size_t)MTOK * (3 * D_);           // o lives in qf tail (576..768)
  float* stE = ws + off; off += (size_t)MTOK * 2;
  float* stD = ws + off; off += (size_t)MTOK * 2;
  float* hp  = ws + off; off += (size_t)B_ * D_;
  float* h1  = ws + off; off += (size_t)B_ * 256;
  float* h2  = ws + off; off += (size_t)B_ * 64;

  // input LN stats + fused LN->in_proj->GELU->posenc
  stats_e_kernel<<<MTOK, 256, 0, stream>>>(emb, stE);
  gemm_f32<true, 3><<<dim3(MTOK / 64, D_ / 64), 256, 0, stream>>>(
      emb, in_proj_w, in_proj_b, stE, in_ln_w, in_ln_b, nullptr, x, MTOK, D_, E_);

  for (int i = 0; i < NL_; ++i) {
    stats_d_kernel<<<MTOK / 4, 256, 0, stream>>>(x, stD);
    gemm_f32<true, 0><<<dim3(MTOK / 64, (3 * D_) / 64), 256, 0, stream>>>(
        x, qkv_w + (size_t)i * 3 * D_ * D_, qkv_b + (size_t)i * 3 * D_, stD,
        ln1w + i * D_, ln1b + i * D_, nullptr, qf, MTOK, 3 * D_, D_);
    attn_kernel<<<B_ / 4, 256, 0, stream>>>(qf, o);
    gemm_f32<false, 2><<<dim3(MTOK / 64, D_ / 64), 256, 0, stream>>>(
        o, aow + (size_t)i * D_ * D_, aob + i * D_, nullptr, nullptr, nullptr,
        x, x, MTOK, D_, D_);
    stats_d_kernel<<<MTOK / 4, 256, 0, stream>>>(x, stD);
    gemm_f32<true, 1><<<dim3(MTOK / 64, FF_ / 64), 256, 0, stream>>>(
        x, ff1w + (size_t)i * FF_ * D_, ff1b + i * FF_, stD,
        ln2w + i * D_, ln2b + i * D_, nullptr, qf, MTOK, FF_, D_);
    gemm_f32<false, 2><<<dim3(MTOK / 64, D_ / 64), 256, 0, stream>>>(
        qf, ff2w + (size_t)i * D_ * FF_, ff2b + i * D_, nullptr, nullptr, nullptr,
        x, x, MTOK, D_, FF_);
  }

  pool_ln_kernel<<<B_ / 4, 256, 0, stream>>>(x, hlnw, hlnb, hp);
  gemm_f32<false, 1><<<dim3(B_ / 64, 256 / 64), 256, 0, stream>>>(
      hp, h1w, h1b, nullptr, nullptr, nullptr, nullptr, h1, B_, 256, D_);
  gemm_f32<false, 1><<<dim3(B_ / 64, 64 / 64), 256, 0, stream>>>(
      h1, h2w, h2b, nullptr, nullptr, nullptr, nullptr, h2, B_, 64, 256);
  head_final_kernel<<<B_ / 4, 256, 0, stream>>>(h2, h3w, h3b, out);
}

// Round 2
// 2222.675 us; speedup vs baseline: 1.3148x; 1.3148x over previous
//
#include <hip/hip_runtime.h>
#include <hip/hip_bf16.h>
#include <math.h>

#define B_   16384
#define S_   4
#define E_   1152
#define D_   192
#define H_   4
#define DH_  48
#define FF_  768
#define NL_  2
#define MTOK (B_ * S_)   // 65536 tokens

typedef __attribute__((ext_vector_type(8))) _Float16 half8;
typedef __attribute__((ext_vector_type(4))) _Float16 half4;
typedef __attribute__((ext_vector_type(4))) float floatx4;

__device__ __forceinline__ float gelu_f(float x) {
  return 0.5f * x * (1.0f + erff(x * 0.70710678118654752f));
}

// ---------------------------------------------------------------------------
// LN stats over E=1152 (one block per token)
// ---------------------------------------------------------------------------
__global__ __launch_bounds__(256) void stats_e_kernel(const float* __restrict__ emb,
                                                      float* __restrict__ st) {
  int m = blockIdx.x;
  const float* row = emb + (size_t)m * E_;
  float sum = 0.f, sq = 0.f;
  for (int idx = threadIdx.x; idx < E_; idx += 256) {
    float v = row[idx];
    sum += v; sq += v * v;
  }
  #pragma unroll
  for (int off = 1; off < 64; off <<= 1) {
    sum += __shfl_xor(sum, off);
    sq  += __shfl_xor(sq, off);
  }
  __shared__ float ls[4], lq[4];
  int wid = threadIdx.x >> 6;
  if ((threadIdx.x & 63) == 0) { ls[wid] = sum; lq[wid] = sq; }
  __syncthreads();
  if (threadIdx.x == 0) {
    float s = ls[0] + ls[1] + ls[2] + ls[3];
    float q = lq[0] + lq[1] + lq[2] + lq[3];
    float mean = s / (float)E_;
    float var  = q / (float)E_ - mean * mean;
    st[2 * m]     = mean;
    st[2 * m + 1] = rsqrtf(var + 1e-5f);
  }
}

// ---------------------------------------------------------------------------
// LN stats over D=192 (one wave per token, 4 waves/block)
// ---------------------------------------------------------------------------
__global__ __launch_bounds__(256) void stats_d_kernel(const float* __restrict__ x,
                                                      float* __restrict__ st) {
  int m = blockIdx.x * 4 + (threadIdx.x >> 6);
  int lane = threadIdx.x & 63;
  const float* row = x + (size_t)m * D_;
  float v0 = row[lane], v1 = row[lane + 64], v2 = row[lane + 128];
  float sum = v0 + v1 + v2;
  #pragma unroll
  for (int off = 1; off < 64; off <<= 1) sum += __shfl_xor(sum, off);
  float mean = sum / (float)D_;
  float d0 = v0 - mean, d1 = v1 - mean, d2 = v2 - mean;
  float vs = d0 * d0 + d1 * d1 + d2 * d2;
  #pragma unroll
  for (int off = 1; off < 64; off <<= 1) vs += __shfl_xor(vs, off);
  if (lane == 0) {
    st[2 * m]     = mean;
    st[2 * m + 1] = rsqrtf(vs / (float)D_ + 1e-5f);
  }
}

// ---------------------------------------------------------------------------
// MFMA GEMM (fp16 operands, fp32 accumulate):
//   C[M,N] = epilogue(op(A)[M,K] @ W[N,K]^T + bias)
// A_F16: A is _Float16 in global (else fp32, converted during staging)
// LN_A : apply (a-mean)*rstd*g+b per A row during staging (fp32 A only)
// EPI  : 0=bias, 1=bias+GELU, 2=bias+residual(fp32 res), 3=bias+GELU+posenc
// C_F16: C stored as _Float16 (else fp32)
// Tiles: BM=128, BN=64, BK=64. 256 threads = 4 waves in 2x2, each wave 64x32
// via 4x2 grid of 16x16x32 MFMA. LDS rows padded to 72 halfs (144 B) so
// fragment ds_read_b128 aliases at most 2-way (free).
// ---------------------------------------------------------------------------
template <bool A_F16, bool LN_A, int EPI, bool C_F16>
__global__ __launch_bounds__(256) void gemm_mfma(
    const void* __restrict__ A_, const float* __restrict__ W,
    const float* __restrict__ bias, const float* __restrict__ stats,
    const float* __restrict__ lng, const float* __restrict__ lnb,
    const float* __restrict__ res, void* __restrict__ C_,
    int M, int N, int K) {
  __shared__ __align__(16) _Float16 As[128][72];
  __shared__ __align__(16) _Float16 Bs[64][72];
  const int tid = threadIdx.x;
  const int m0 = blockIdx.x * 128;
  const int n0 = blockIdx.y * 64;
  // staging coords
  const int r_a = tid >> 1;            // 0..127
  const int c_a = (tid & 1) * 32;      // 0 / 32
  const int r_b = tid >> 2;            // 0..63
  const int c_b = (tid & 3) * 16;      // 0/16/32/48
  // compute coords
  const int w    = tid >> 6;
  const int lane = tid & 63;
  const int ln16 = lane & 15;
  const int quad = lane >> 4;
  const int wm = (w >> 1) * 64;        // wave M offset in tile
  const int wn = (w & 1) * 32;         // wave N offset in tile

  floatx4 acc[4][2] = {};
  float sm = 0.f, srs = 0.f;
  if constexpr (LN_A) {
    sm  = stats[2 * (m0 + r_a)];
    srs = stats[2 * (m0 + r_a) + 1];
  }
  const float*     ArowF = (const float*)A_ + (size_t)(m0 + r_a) * K;
  const _Float16*  ArowH = (const _Float16*)A_ + (size_t)(m0 + r_a) * K;
  const float*     Wrow  = W + (size_t)(n0 + r_b) * K;

  for (int k0 = 0; k0 < K; k0 += 64) {
    half8 stA[4];
    uint4 stAh[4];
    if constexpr (A_F16) {
      const uint4* p = (const uint4*)(ArowH + k0 + c_a);
      #pragma unroll
      for (int i = 0; i < 4; ++i) stAh[i] = p[i];
    } else {
      #pragma unroll
      for (int i = 0; i < 4; ++i) {
        float4 a0 = *(const float4*)(ArowF + k0 + c_a + i * 8);
        float4 a1 = *(const float4*)(ArowF + k0 + c_a + i * 8 + 4);
        if constexpr (LN_A) {
          const float4 g0 = *(const float4*)(lng + k0 + c_a + i * 8);
          const float4 g1 = *(const float4*)(lng + k0 + c_a + i * 8 + 4);
          const float4 b0 = *(const float4*)(lnb + k0 + c_a + i * 8);
          const float4 b1 = *(const float4*)(lnb + k0 + c_a + i * 8 + 4);
          a0.x = (a0.x - sm) * srs * g0.x + b0.x;
          a0.y = (a0.y - sm) * srs * g0.y + b0.y;
          a0.z = (a0.z - sm) * srs * g0.z + b0.z;
          a0.w = (a0.w - sm) * srs * g0.w + b0.w;
          a1.x = (a1.x - sm) * srs * g1.x + b1.x;
          a1.y = (a1.y - sm) * srs * g1.y + b1.y;
          a1.z = (a1.z - sm) * srs * g1.z + b1.z;
          a1.w = (a1.w - sm) * srs * g1.w + b1.w;
        }
        half8 h;
        h[0] = (_Float16)a0.x; h[1] = (_Float16)a0.y;
        h[2] = (_Float16)a0.z; h[3] = (_Float16)a0.w;
        h[4] = (_Float16)a1.x; h[5] = (_Float16)a1.y;
        h[6] = (_Float16)a1.z; h[7] = (_Float16)a1.w;
        stA[i] = h;
      }
    }
    half8 stB[2];
    #pragma unroll
    for (int i = 0; i < 2; ++i) {
      float4 b0 = *(const float4*)(Wrow + k0 + c_b + i * 8);
      float4 b1 = *(const float4*)(Wrow + k0 + c_b + i * 8 + 4);
      half8 h;
      h[0] = (_Float16)b0.x; h[1] = (_Float16)b0.y;
      h[2] = (_Float16)b0.z; h[3] = (_Float16)b0.w;
      h[4] = (_Float16)b1.x; h[5] = (_Float16)b1.y;
      h[6] = (_Float16)b1.z; h[7] = (_Float16)b1.w;
      stB[i] = h;
    }
    __syncthreads();
    if constexpr (A_F16) {
      #pragma unroll
      for (int i = 0; i < 4; ++i) *(uint4*)&As[r_a][c_a + i * 8] = stAh[i];
    } else {
      #pragma unroll
      for (int i = 0; i < 4; ++i) *(half8*)&As[r_a][c_a + i * 8] = stA[i];
    }
    #pragma unroll
    for (int i = 0; i < 2; ++i) *(half8*)&Bs[r_b][c_b + i * 8] = stB[i];
    __syncthreads();
    #pragma unroll
    for (int kk = 0; kk < 64; kk += 32) {
      half8 af[4], bf[2];
      #pragma unroll
      for (int mt = 0; mt < 4; ++mt)
        af[mt] = *(const half8*)&As[wm + mt * 16 + ln16][kk + quad * 8];
      #pragma unroll
      for (int nt = 0; nt < 2; ++nt)
        bf[nt] = *(const half8*)&Bs[wn + nt * 16 + ln16][kk + quad * 8];
      #pragma unroll
      for (int mt = 0; mt < 4; ++mt)
        #pragma unroll
        for (int nt = 0; nt < 2; ++nt)
          acc[mt][nt] = __builtin_amdgcn_mfma_f32_16x16x32_f16(
              af[mt], bf[nt], acc[mt][nt], 0, 0, 0);
    }
  }

  // epilogue
  float*    Cf = (float*)C_;
  _Float16* Ch = (_Float16*)C_;
  #pragma unroll
  for (int nt = 0; nt < 2; ++nt) {
    const int col = n0 + wn + nt * 16 + ln16;
    const float bv = bias[col];
    float pe_s = 0.f, pe_c = 0.f;
    if constexpr (EPI == 3) {
      int jc = col & ~1;
      float div = expf((float)jc * (-0.047970522770709292f));
      pe_s = div;  // angle = (row&3) * div, applied per row below
      pe_c = (float)(col & 1);
    }
    #pragma unroll
    for (int mt = 0; mt < 4; ++mt) {
      #pragma unroll
      for (int r = 0; r < 4; ++r) {
        const int row = m0 + wm + mt * 16 + quad * 4 + r;
        float v = acc[mt][nt][r] + bv;
        if constexpr (EPI == 1 || EPI == 3) v = gelu_f(v);
        if constexpr (EPI == 3) {
          float ang = (float)(row & 3) * pe_s;
          v += (pe_c != 0.f) ? cosf(ang) : sinf(ang);
        }
        if constexpr (EPI == 2) v += res[(size_t)row * N + col];
        if constexpr (C_F16) Ch[(size_t)row * N + col] = (_Float16)v;
        else                 Cf[(size_t)row * N + col] = v;
      }
    }
  }
}

// ---------------------------------------------------------------------------
// Attention: S=4, H=4, DH=48. 4 samples per block, one wave per sample.
// qkv (fp16) row layout per token: [q(192) | k(192) | v(192)].
// ---------------------------------------------------------------------------
__global__ __launch_bounds__(256) void attn_kernel(const _Float16* __restrict__ qkv,
                                                   _Float16* __restrict__ o) {
  __shared__ float sq[4][4][576];
  __shared__ float sp[4][4][4][4];
  int tid = threadIdx.x;
  int b0 = blockIdx.x * 4;
  const _Float16* src = qkv + (size_t)b0 * 4 * 576;
  float* dst = &sq[0][0][0];
  #pragma unroll
  for (int t = 0; t < 9; ++t) {
    int i = (tid + t * 256) * 4;             // 9216 halfs, 4 per thread-iter
    half4 hv = *(const half4*)(src + i);
    dst[i + 0] = (float)hv[0]; dst[i + 1] = (float)hv[1];
    dst[i + 2] = (float)hv[2]; dst[i + 3] = (float)hv[3];
  }
  __syncthreads();
  int sg = tid >> 6;
  int lane = tid & 63;
  int h = lane >> 4, i = (lane >> 2) & 3, j = lane & 3;
  const float* qp = &sq[sg][i][h * 48];
  const float* kp = &sq[sg][j][192 + h * 48];
  float s = 0.f;
  #pragma unroll
  for (int d = 0; d < 48; ++d) s += qp[d] * kp[d];
  s *= 0.14433756729740643f;  // 1/sqrt(48)
  float mx = fmaxf(s, __shfl_xor(s, 1));
  mx = fmaxf(mx, __shfl_xor(mx, 2));
  float e = expf(s - mx);
  float sum = e + __shfl_xor(e, 1);
  sum += __shfl_xor(sum, 2);
  sp[sg][h][i][j] = e / sum;
  __syncthreads();
  #pragma unroll
  for (int ii = 0; ii < 4; ++ii) {
    #pragma unroll
    for (int cc = 0; cc < 3; ++cc) {
      int c = lane + cc * 64;
      int hh = c / 48;
      float acc = 0.f;
      #pragma unroll
      for (int jj = 0; jj < 4; ++jj)
        acc += sp[sg][hh][ii][jj] * sq[sg][jj][384 + c];
      o[((size_t)(b0 + sg) * 4 + ii) * D_ + c] = (_Float16)acc;
    }
  }
}

// ---------------------------------------------------------------------------
// fp32 GEMM (head only): C[M,N] = epi(A[M,K] @ W[N,K]^T + bias)
// EPI: 0 bias, 1 bias+GELU. 64x64x16 tiles.
// ---------------------------------------------------------------------------
template <int EPI>
__global__ __launch_bounds__(256) void gemm_f32(
    const float* __restrict__ A, const float* __restrict__ W,
    const float* __restrict__ bias, float* __restrict__ C,
    int M, int N, int K) {
  __shared__ float As[16][68];
  __shared__ float Bs[16][68];
  const int tid = threadIdx.x;
  const int m0 = blockIdx.x * 64;
  const int n0 = blockIdx.y * 64;
  const int tx = tid & 15, ty = tid >> 4;
  const int lr = tid >> 2;
  const int lk = (tid & 3) << 2;
  float acc[4][4] = {};
  const float* Arow = A + (size_t)(m0 + lr) * K;
  const float* Wrow = W + (size_t)(n0 + lr) * K;
  for (int k0 = 0; k0 < K; k0 += 16) {
    float4 av = *(const float4*)(Arow + k0 + lk);
    float4 wv = *(const float4*)(Wrow + k0 + lk);
    __syncthreads();
    As[lk + 0][lr] = av.x; As[lk + 1][lr] = av.y;
    As[lk + 2][lr] = av.z; As[lk + 3][lr] = av.w;
    Bs[lk + 0][lr] = wv.x; Bs[lk + 1][lr] = wv.y;
    Bs[lk + 2][lr] = wv.z; Bs[lk + 3][lr] = wv.w;
    __syncthreads();
    #pragma unroll
    for (int kk = 0; kk < 16; ++kk) {
      float4 a = *(const float4*)&As[kk][ty * 4];
      float4 b = *(const float4*)&Bs[kk][tx * 4];
      acc[0][0] += a.x * b.x; acc[0][1] += a.x * b.y; acc[0][2] += a.x * b.z; acc[0][3] += a.x * b.w;
      acc[1][0] += a.y * b.x; acc[1][1] += a.y * b.y; acc[1][2] += a.y * b.z; acc[1][3] += a.y * b.w;
      acc[2][0] += a.z * b.x; acc[2][1] += a.z * b.y; acc[2][2] += a.z * b.z; acc[2][3] += a.z * b.w;
      acc[3][0] += a.w * b.x; acc[3][1] += a.w * b.y; acc[3][2] += a.w * b.z; acc[3][3] += a.w * b.w;
    }
  }
  float4 bv = *(const float4*)(bias + n0 + tx * 4);
  #pragma unroll
  for (int i = 0; i < 4; ++i) {
    int m = m0 + ty * 4 + i;
    float v0 = acc[i][0] + bv.x, v1 = acc[i][1] + bv.y;
    float v2 = acc[i][2] + bv.z, v3 = acc[i][3] + bv.w;
    if constexpr (EPI == 1) {
      v0 = gelu_f(v0); v1 = gelu_f(v1); v2 = gelu_f(v2); v3 = gelu_f(v3);
    }
    float4 ov; ov.x = v0; ov.y = v1; ov.z = v2; ov.w = v3;
    *(float4*)(C + (size_t)m * N + n0 + tx * 4) = ov;
  }
}

// ---------------------------------------------------------------------------
// mean-pool over S=4 + head LN (one wave per sample)
// ---------------------------------------------------------------------------
__global__ __launch_bounds__(256) void pool_ln_kernel(const float* __restrict__ x,
                                                      const float* __restrict__ g,
                                                      const float* __restrict__ b,
                                                      float* __restrict__ hout) {
  int bi = blockIdx.x * 4 + (threadIdx.x >> 6);
  int lane = threadIdx.x & 63;
  const float* row = x + (size_t)bi * 4 * D_;
  float vals[3];
  float sum = 0.f;
  #pragma unroll
  for (int cc = 0; cc < 3; ++cc) {
    int d = lane + cc * 64;
    float v = 0.25f * (row[d] + row[D_ + d] + row[2 * D_ + d] + row[3 * D_ + d]);
    vals[cc] = v; sum += v;
  }
  #pragma unroll
  for (int off = 1; off < 64; off <<= 1) sum += __shfl_xor(sum, off);
  float mean = sum / (float)D_;
  float vs = 0.f;
  #pragma unroll
  for (int cc = 0; cc < 3; ++cc) { float d0 = vals[cc] - mean; vs += d0 * d0; }
  #pragma unroll
  for (int off = 1; off < 64; off <<= 1) vs += __shfl_xor(vs, off);
  float rstd = rsqrtf(vs / (float)D_ + 1e-5f);
  #pragma unroll
  for (int cc = 0; cc < 3; ++cc) {
    int d = lane + cc * 64;
    hout[(size_t)bi * D_ + d] = (vals[cc] - mean) * rstd * g[d] + b[d];
  }
}

// ---------------------------------------------------------------------------
// final: out[b] = h2[b,:64] . h3_w + h3_b  (one wave per sample)
// ---------------------------------------------------------------------------
__global__ __launch_bounds__(256) void head_final_kernel(const float* __restrict__ h2,
                                                         const float* __restrict__ w,
                                                         const float* __restrict__ b,
                                                         float* __restrict__ out) {
  int bi = blockIdx.x * 4 + (threadIdx.x >> 6);
  int lane = threadIdx.x & 63;
  float v = h2[(size_t)bi * 64 + lane] * w[lane];
  #pragma unroll
  for (int off = 1; off < 64; off <<= 1) v += __shfl_xor(v, off);
  if (lane == 0) out[bi] = v + b[0];
}

// ---------------------------------------------------------------------------
extern "C" void kernel_launch(void* const* d_in, const int* in_sizes, int n_in,
                              void* d_out, int out_size, void* d_ws, size_t ws_size,
                              hipStream_t stream) {
  (void)in_sizes; (void)n_in; (void)out_size; (void)ws_size;
  const float* emb       = (const float*)d_in[0];
  const float* in_ln_w   = (const float*)d_in[1];
  const float* in_ln_b   = (const float*)d_in[2];
  const float* in_proj_w = (const float*)d_in[3];
  const float* in_proj_b = (const float*)d_in[4];
  const float* qkv_w     = (const float*)d_in[5];
  const float* qkv_b     = (const float*)d_in[6];
  const float* aow       = (const float*)d_in[7];
  const float* aob       = (const float*)d_in[8];
  const float* ln1w      = (const float*)d_in[9];
  const float* ln1b      = (const float*)d_in[10];
  const float* ln2w      = (const float*)d_in[11];
  const float* ln2b      = (const float*)d_in[12];
  const float* ff1w      = (const float*)d_in[13];
  const float* ff1b      = (const float*)d_in[14];
  const float* ff2w      = (const float*)d_in[15];
  const float* ff2b      = (const float*)d_in[16];
  const float* hlnw      = (const float*)d_in[17];
  const float* hlnb      = (const float*)d_in[18];
  const float* h1w       = (const float*)d_in[19];
  const float* h1b       = (const float*)d_in[20];
  const float* h2w       = (const float*)d_in[21];
  const float* h2b       = (const float*)d_in[22];
  const float* h3w       = (const float*)d_in[23];
  const float* h3b       = (const float*)d_in[24];
  float* out = (float*)d_out;

  // workspace layout; residual adds are in-place on fp32 x.
  float* ws = (float*)d_ws;
  size_t off = 0;
  float* x = ws + off; off += (size_t)MTOK * D_;           // fp32 residual stream
  _Float16* qf = (_Float16*)(ws + off);                    // fp16: qkv(576)/ff(768)
  off += (size_t)MTOK * FF_ / 2 + 64;
  _Float16* o = qf + (size_t)MTOK * (3 * D_);              // o in qf tail cols 576..768
  float* stE = ws + off; off += (size_t)MTOK * 2;
  float* stD = ws + off; off += (size_t)MTOK * 2;
  float* hp  = ws + off; off += (size_t)B_ * D_;
  float* h1  = ws + off; off += (size_t)B_ * 256;
  float* h2  = ws + off; off += (size_t)B_ * 64;

  // input LN stats + fused LN->in_proj->GELU->posenc  (C = fp32 x)
  stats_e_kernel<<<MTOK, 256, 0, stream>>>(emb, stE);
  gemm_mfma<false, true, 3, false><<<dim3(MTOK / 128, D_ / 64), 256, 0, stream>>>(
      emb, in_proj_w, in_proj_b, stE, in_ln_w, in_ln_b, nullptr, x, MTOK, D_, E_);

  for (int i = 0; i < NL_; ++i) {
    stats_d_kernel<<<MTOK / 4, 256, 0, stream>>>(x, stD);
    gemm_mfma<false, true, 0, true><<<dim3(MTOK / 128, (3 * D_) / 64), 256, 0, stream>>>(
        x, qkv_w + (size_t)i * 3 * D_ * D_, qkv_b + (size_t)i * 3 * D_, stD,
        ln1w + i * D_, ln1b + i * D_, nullptr, qf, MTOK, 3 * D_, D_);
    attn_kernel<<<B_ / 4, 256, 0, stream>>>(qf, o);
    gemm_mfma<true, false, 2, false><<<dim3(MTOK / 128, D_ / 64), 256, 0, stream>>>(
        o, aow + (size_t)i * D_ * D_, aob + i * D_, nullptr, nullptr, nullptr,
        x, x, MTOK, D_, D_);
    stats_d_kernel<<<MTOK / 4, 256, 0, stream>>>(x, stD);
    gemm_mfma<false, true, 1, true><<<dim3(MTOK / 128, FF_ / 64), 256, 0, stream>>>(
        x, ff1w + (size_t)i * FF_ * D_, ff1b + i * FF_, stD,
        ln2w + i * D_, ln2b + i * D_, nullptr, qf, MTOK, FF_, D_);
    gemm_mfma<true, false, 2, false><<<dim3(MTOK / 128, D_ / 64), 256, 0, stream>>>(
        qf, ff2w + (size_t)i * D_ * FF_, ff2b + i * D_, nullptr, nullptr, nullptr,
        x, x, MTOK, D_, FF_);
  }

  pool_ln_kernel<<<B_ / 4, 256, 0, stream>>>(x, hlnw, hlnb, hp);
  gemm_f32<1><<<dim3(B_ / 64, 256 / 64), 256, 0, stream>>>(hp, h1w, h1b, h1, B_, 256, D_);
  gemm_f32<1><<<dim3(B_ / 64, 64 / 64), 256, 0, stream>>>(h1, h2w, h2b, h2, B_, 64, 256);
  head_final_kernel<<<B_ / 4, 256, 0, stream>>>(h2, h3w, h3b, out);
}

// Round 3
// 1609.711 us; speedup vs baseline: 1.8155x; 1.3808x over previous
//
#include <hip/hip_runtime.h>
#include <hip/hip_bf16.h>
#include <math.h>

#define B_   16384
#define S_   4
#define E_   1152
#define D_   192
#define H_   4
#define DH_  48
#define FF_  768
#define NL_  2
#define MTOK (B_ * S_)   // 65536 tokens

typedef __attribute__((ext_vector_type(8))) _Float16 half8;
typedef __attribute__((ext_vector_type(4))) _Float16 half4;
typedef __attribute__((ext_vector_type(4))) float floatx4;

__device__ __forceinline__ float gelu_f(float x) {
  return 0.5f * x * (1.0f + erff(x * 0.70710678118654752f));
}

// ---------------------------------------------------------------------------
// LN stats over E=1152 (one block per token)
// ---------------------------------------------------------------------------
__global__ __launch_bounds__(256) void stats_e_kernel(const float* __restrict__ emb,
                                                      float* __restrict__ st) {
  int m = blockIdx.x;
  const float* row = emb + (size_t)m * E_;
  float sum = 0.f, sq = 0.f;
  for (int idx = threadIdx.x; idx < E_; idx += 256) {
    float v = row[idx];
    sum += v; sq += v * v;
  }
  #pragma unroll
  for (int off = 1; off < 64; off <<= 1) {
    sum += __shfl_xor(sum, off);
    sq  += __shfl_xor(sq, off);
  }
  __shared__ float ls[4], lq[4];
  int wid = threadIdx.x >> 6;
  if ((threadIdx.x & 63) == 0) { ls[wid] = sum; lq[wid] = sq; }
  __syncthreads();
  if (threadIdx.x == 0) {
    float s = ls[0] + ls[1] + ls[2] + ls[3];
    float q = lq[0] + lq[1] + lq[2] + lq[3];
    float mean = s / (float)E_;
    float var  = q / (float)E_ - mean * mean;
    st[2 * m]     = mean;
    st[2 * m + 1] = rsqrtf(var + 1e-5f);
  }
}

// ---------------------------------------------------------------------------
// Full-N MFMA GEMM for N=192 outputs: C[M,192] = epi(op(A)[M,K] @ W[192,K]^T)
// One block owns 64 complete output rows -> A read exactly once from HBM,
// and per-row LN stats (mean, rstd over the 192 cols) can be fused into the
// epilogue (STATS), eliminating the separate stats pass over x.
// A_F16: A is fp16; else fp32 (optionally LN'd with stats_in/lng/lnb).
// EPI: 2 = bias+residual(fp32, may alias C); 3 = bias+GELU+posenc.
// Block: 256 thr = 4 waves; wave w covers rows 0..63 x cols w*48..w*48+47
// via 4x3 grid of 16x16x32 fp16 MFMA. BK=64.
// ---------------------------------------------------------------------------
template <bool A_F16, bool LN_A, int EPI, bool STATS>
__global__ __launch_bounds__(256) void gemm_n192(
    const void* __restrict__ A_, const float* __restrict__ W,
    const float* __restrict__ bias, const float* __restrict__ stats_in,
    const float* __restrict__ lng, const float* __restrict__ lnb,
    const float* __restrict__ res, float* __restrict__ C,
    float* __restrict__ stats_out, int K) {
  __shared__ __align__(16) _Float16 As[64][72];
  __shared__ __align__(16) _Float16 Bs[192][72];
  __shared__ float red[4][64][2];
  const int tid = threadIdx.x;
  const int m0 = blockIdx.x * 64;
  const int r_a = tid >> 2;           // 0..63 (A row; also base B row)
  const int c_a = (tid & 3) * 16;     // half-offset within BK=64: 0/16/32/48
  const int w = tid >> 6, lane = tid & 63;
  const int ln16 = lane & 15, quad = lane >> 4;
  const int wn = w * 48;

  floatx4 acc[4][3] = {};
  float sm = 0.f, srs = 0.f;
  if constexpr (LN_A) {
    sm  = stats_in[2 * (m0 + r_a)];
    srs = stats_in[2 * (m0 + r_a) + 1];
  }
  const float*    ArowF = (const float*)A_ + (size_t)(m0 + r_a) * K;
  const _Float16* ArowH = (const _Float16*)A_ + (size_t)(m0 + r_a) * K;

  for (int k0 = 0; k0 < K; k0 += 64) {
    // ---- load A (16 halfs per thread) ----
    uint4 uA[2];
    half8 hA[2];
    if constexpr (A_F16) {
      const uint4* p = (const uint4*)(ArowH + k0 + c_a);
      uA[0] = p[0]; uA[1] = p[1];
    } else {
      float4 a[4];
      #pragma unroll
      for (int j = 0; j < 4; ++j) a[j] = *(const float4*)(ArowF + k0 + c_a + j * 4);
      if constexpr (LN_A) {
        #pragma unroll
        for (int j = 0; j < 4; ++j) {
          float4 g  = *(const float4*)(lng + k0 + c_a + j * 4);
          float4 bb = *(const float4*)(lnb + k0 + c_a + j * 4);
          a[j].x = (a[j].x - sm) * srs * g.x + bb.x;
          a[j].y = (a[j].y - sm) * srs * g.y + bb.y;
          a[j].z = (a[j].z - sm) * srs * g.z + bb.z;
          a[j].w = (a[j].w - sm) * srs * g.w + bb.w;
        }
      }
      #pragma unroll
      for (int j = 0; j < 2; ++j) {
        half8 h;
        h[0] = (_Float16)a[2*j].x;   h[1] = (_Float16)a[2*j].y;
        h[2] = (_Float16)a[2*j].z;   h[3] = (_Float16)a[2*j].w;
        h[4] = (_Float16)a[2*j+1].x; h[5] = (_Float16)a[2*j+1].y;
        h[6] = (_Float16)a[2*j+1].z; h[7] = (_Float16)a[2*j+1].w;
        hA[j] = h;
      }
    }
    // ---- load B: rows r_a, r_a+64, r_a+128 (fp32 W, L2-resident) ----
    half8 hB[3][2];
    #pragma unroll
    for (int i = 0; i < 3; ++i) {
      const float* wr = W + (size_t)(r_a + i * 64) * K + k0 + c_a;
      float4 b0 = *(const float4*)(wr + 0);
      float4 b1 = *(const float4*)(wr + 4);
      float4 b2 = *(const float4*)(wr + 8);
      float4 b3 = *(const float4*)(wr + 12);
      half8 h0, h1;
      h0[0] = (_Float16)b0.x; h0[1] = (_Float16)b0.y; h0[2] = (_Float16)b0.z; h0[3] = (_Float16)b0.w;
      h0[4] = (_Float16)b1.x; h0[5] = (_Float16)b1.y; h0[6] = (_Float16)b1.z; h0[7] = (_Float16)b1.w;
      h1[0] = (_Float16)b2.x; h1[1] = (_Float16)b2.y; h1[2] = (_Float16)b2.z; h1[3] = (_Float16)b2.w;
      h1[4] = (_Float16)b3.x; h1[5] = (_Float16)b3.y; h1[6] = (_Float16)b3.z; h1[7] = (_Float16)b3.w;
      hB[i][0] = h0; hB[i][1] = h1;
    }
    __syncthreads();
    if constexpr (A_F16) {
      *(uint4*)&As[r_a][c_a]     = uA[0];
      *(uint4*)&As[r_a][c_a + 8] = uA[1];
    } else {
      *(half8*)&As[r_a][c_a]     = hA[0];
      *(half8*)&As[r_a][c_a + 8] = hA[1];
    }
    #pragma unroll
    for (int i = 0; i < 3; ++i) {
      *(half8*)&Bs[r_a + i * 64][c_a]     = hB[i][0];
      *(half8*)&Bs[r_a + i * 64][c_a + 8] = hB[i][1];
    }
    __syncthreads();
    #pragma unroll
    for (int kk = 0; kk < 64; kk += 32) {
      half8 af[4], bf[3];
      #pragma unroll
      for (int mt = 0; mt < 4; ++mt)
        af[mt] = *(const half8*)&As[mt * 16 + ln16][kk + quad * 8];
      #pragma unroll
      for (int nt = 0; nt < 3; ++nt)
        bf[nt] = *(const half8*)&Bs[wn + nt * 16 + ln16][kk + quad * 8];
      #pragma unroll
      for (int mt = 0; mt < 4; ++mt)
        #pragma unroll
        for (int nt = 0; nt < 3; ++nt)
          acc[mt][nt] = __builtin_amdgcn_mfma_f32_16x16x32_f16(
              af[mt], bf[nt], acc[mt][nt], 0, 0, 0);
    }
  }

  // ---- epilogue ----
  float bv[3], pe_val[3][4];
  #pragma unroll
  for (int nt = 0; nt < 3; ++nt) {
    int col = wn + nt * 16 + ln16;
    bv[nt] = bias[col];
    if constexpr (EPI == 3) {
      float divv = expf((float)(col & ~1) * (-0.047970522770709292f));
      bool odd = (col & 1) != 0;
      #pragma unroll
      for (int r = 0; r < 4; ++r) {
        float ang = (float)r * divv;
        pe_val[nt][r] = odd ? cosf(ang) : sinf(ang);
      }
    }
  }
  #pragma unroll
  for (int mt = 0; mt < 4; ++mt) {
    #pragma unroll
    for (int r = 0; r < 4; ++r) {
      const int row = m0 + mt * 16 + quad * 4 + r;  // row & 3 == r
      float s = 0.f, q = 0.f;
      #pragma unroll
      for (int nt = 0; nt < 3; ++nt) {
        const int col = wn + nt * 16 + ln16;
        float v = acc[mt][nt][r] + bv[nt];
        if constexpr (EPI == 3) { v = gelu_f(v); v += pe_val[nt][r]; }
        if constexpr (EPI == 2) v += res[(size_t)row * D_ + col];
        C[(size_t)row * D_ + col] = v;
        if constexpr (STATS) { s += v; q += v * v; }
      }
      if constexpr (STATS) {
        #pragma unroll
        for (int off = 1; off < 16; off <<= 1) {
          s += __shfl_xor(s, off);
          q += __shfl_xor(q, off);
        }
        if (ln16 == 0) {
          red[w][mt * 16 + quad * 4 + r][0] = s;
          red[w][mt * 16 + quad * 4 + r][1] = q;
        }
      }
    }
  }
  if constexpr (STATS) {
    __syncthreads();
    if (tid < 64) {
      float s = red[0][tid][0] + red[1][tid][0] + red[2][tid][0] + red[3][tid][0];
      float q = red[0][tid][1] + red[1][tid][1] + red[2][tid][1] + red[3][tid][1];
      float mean = s * (1.f / 192.f);
      float var  = q * (1.f / 192.f) - mean * mean;
      stats_out[2 * (m0 + tid)]     = mean;
      stats_out[2 * (m0 + tid) + 1] = rsqrtf(var + 1e-5f);
    }
  }
}

// ---------------------------------------------------------------------------
// Wide-N MFMA GEMM (qkv N=576, ff1 N=768): C_f16[M,N] = epi(LN(A)[M,K] @ W^T)
// Grid: x = N-tiles (fastest) so same-A blocks are temporally adjacent and
// A re-reads are L3-served. EPI: 0=bias, 1=bias+GELU.
// BM=128, BN=64, BK=64. 4 waves 2x2, wave = 64x32 via 4x2 MFMA tiles.
// ---------------------------------------------------------------------------
template <int EPI>
__global__ __launch_bounds__(256) void gemm_mfma(
    const float* __restrict__ A, const float* __restrict__ W,
    const float* __restrict__ bias, const float* __restrict__ stats,
    const float* __restrict__ lng, const float* __restrict__ lnb,
    _Float16* __restrict__ C, int M, int N, int K) {
  __shared__ __align__(16) _Float16 As[128][72];
  __shared__ __align__(16) _Float16 Bs[64][72];
  const int tid = threadIdx.x;
  const int m0 = blockIdx.y * 128;
  const int n0 = blockIdx.x * 64;
  const int r_a = tid >> 1;
  const int c_a = (tid & 1) * 32;
  const int r_b = tid >> 2;
  const int c_b = (tid & 3) * 16;
  const int w    = tid >> 6;
  const int lane = tid & 63;
  const int ln16 = lane & 15;
  const int quad = lane >> 4;
  const int wm = (w >> 1) * 64;
  const int wn = (w & 1) * 32;

  floatx4 acc[4][2] = {};
  const float sm  = stats[2 * (m0 + r_a)];
  const float srs = stats[2 * (m0 + r_a) + 1];
  const float* Arow = A + (size_t)(m0 + r_a) * K;
  const float* Wrow = W + (size_t)(n0 + r_b) * K;

  for (int k0 = 0; k0 < K; k0 += 64) {
    half8 stA[4];
    #pragma unroll
    for (int i = 0; i < 4; ++i) {
      float4 a0 = *(const float4*)(Arow + k0 + c_a + i * 8);
      float4 a1 = *(const float4*)(Arow + k0 + c_a + i * 8 + 4);
      const float4 g0 = *(const float4*)(lng + k0 + c_a + i * 8);
      const float4 g1 = *(const float4*)(lng + k0 + c_a + i * 8 + 4);
      const float4 b0 = *(const float4*)(lnb + k0 + c_a + i * 8);
      const float4 b1 = *(const float4*)(lnb + k0 + c_a + i * 8 + 4);
      a0.x = (a0.x - sm) * srs * g0.x + b0.x;
      a0.y = (a0.y - sm) * srs * g0.y + b0.y;
      a0.z = (a0.z - sm) * srs * g0.z + b0.z;
      a0.w = (a0.w - sm) * srs * g0.w + b0.w;
      a1.x = (a1.x - sm) * srs * g1.x + b1.x;
      a1.y = (a1.y - sm) * srs * g1.y + b1.y;
      a1.z = (a1.z - sm) * srs * g1.z + b1.z;
      a1.w = (a1.w - sm) * srs * g1.w + b1.w;
      half8 h;
      h[0] = (_Float16)a0.x; h[1] = (_Float16)a0.y;
      h[2] = (_Float16)a0.z; h[3] = (_Float16)a0.w;
      h[4] = (_Float16)a1.x; h[5] = (_Float16)a1.y;
      h[6] = (_Float16)a1.z; h[7] = (_Float16)a1.w;
      stA[i] = h;
    }
    half8 stB[2];
    #pragma unroll
    for (int i = 0; i < 2; ++i) {
      float4 b0 = *(const float4*)(Wrow + k0 + c_b + i * 8);
      float4 b1 = *(const float4*)(Wrow + k0 + c_b + i * 8 + 4);
      half8 h;
      h[0] = (_Float16)b0.x; h[1] = (_Float16)b0.y;
      h[2] = (_Float16)b0.z; h[3] = (_Float16)b0.w;
      h[4] = (_Float16)b1.x; h[5] = (_Float16)b1.y;
      h[6] = (_Float16)b1.z; h[7] = (_Float16)b1.w;
      stB[i] = h;
    }
    __syncthreads();
    #pragma unroll
    for (int i = 0; i < 4; ++i) *(half8*)&As[r_a][c_a + i * 8] = stA[i];
    #pragma unroll
    for (int i = 0; i < 2; ++i) *(half8*)&Bs[r_b][c_b + i * 8] = stB[i];
    __syncthreads();
    #pragma unroll
    for (int kk = 0; kk < 64; kk += 32) {
      half8 af[4], bf[2];
      #pragma unroll
      for (int mt = 0; mt < 4; ++mt)
        af[mt] = *(const half8*)&As[wm + mt * 16 + ln16][kk + quad * 8];
      #pragma unroll
      for (int nt = 0; nt < 2; ++nt)
        bf[nt] = *(const half8*)&Bs[wn + nt * 16 + ln16][kk + quad * 8];
      #pragma unroll
      for (int mt = 0; mt < 4; ++mt)
        #pragma unroll
        for (int nt = 0; nt < 2; ++nt)
          acc[mt][nt] = __builtin_amdgcn_mfma_f32_16x16x32_f16(
              af[mt], bf[nt], acc[mt][nt], 0, 0, 0);
    }
  }

  #pragma unroll
  for (int nt = 0; nt < 2; ++nt) {
    const int col = n0 + wn + nt * 16 + ln16;
    const float bv = bias[col];
    #pragma unroll
    for (int mt = 0; mt < 4; ++mt) {
      #pragma unroll
      for (int r = 0; r < 4; ++r) {
        const int row = m0 + wm + mt * 16 + quad * 4 + r;
        float v = acc[mt][nt][r] + bv;
        if constexpr (EPI == 1) v = gelu_f(v);
        C[(size_t)row * N + col] = (_Float16)v;
      }
    }
  }
}

// ---------------------------------------------------------------------------
// Attention: S=4, H=4, DH=48. 4 samples per block, one wave per sample.
// qkv (fp16) row layout per token: [q(192) | k(192) | v(192)].
// ---------------------------------------------------------------------------
__global__ __launch_bounds__(256) void attn_kernel(const _Float16* __restrict__ qkv,
                                                   _Float16* __restrict__ o) {
  __shared__ float sq[4][4][576];
  __shared__ float sp[4][4][4][4];
  int tid = threadIdx.x;
  int b0 = blockIdx.x * 4;
  const _Float16* src = qkv + (size_t)b0 * 4 * 576;
  float* dst = &sq[0][0][0];
  #pragma unroll
  for (int t = 0; t < 9; ++t) {
    int i = (tid + t * 256) * 4;
    half4 hv = *(const half4*)(src + i);
    dst[i + 0] = (float)hv[0]; dst[i + 1] = (float)hv[1];
    dst[i + 2] = (float)hv[2]; dst[i + 3] = (float)hv[3];
  }
  __syncthreads();
  int sg = tid >> 6;
  int lane = tid & 63;
  int h = lane >> 4, i = (lane >> 2) & 3, j = lane & 3;
  const float* qp = &sq[sg][i][h * 48];
  const float* kp = &sq[sg][j][192 + h * 48];
  float s = 0.f;
  #pragma unroll
  for (int d = 0; d < 48; ++d) s += qp[d] * kp[d];
  s *= 0.14433756729740643f;  // 1/sqrt(48)
  float mx = fmaxf(s, __shfl_xor(s, 1));
  mx = fmaxf(mx, __shfl_xor(mx, 2));
  float e = expf(s - mx);
  float sum = e + __shfl_xor(e, 1);
  sum += __shfl_xor(sum, 2);
  sp[sg][h][i][j] = e / sum;
  __syncthreads();
  #pragma unroll
  for (int ii = 0; ii < 4; ++ii) {
    #pragma unroll
    for (int cc = 0; cc < 3; ++cc) {
      int c = lane + cc * 64;
      int hh = c / 48;
      float acc = 0.f;
      #pragma unroll
      for (int jj = 0; jj < 4; ++jj)
        acc += sp[sg][hh][ii][jj] * sq[sg][jj][384 + c];
      o[((size_t)(b0 + sg) * 4 + ii) * D_ + c] = (_Float16)acc;
    }
  }
}

// ---------------------------------------------------------------------------
// fp32 GEMM (head only): C[M,N] = epi(A[M,K] @ W[N,K]^T + bias)
// ---------------------------------------------------------------------------
template <int EPI>
__global__ __launch_bounds__(256) void gemm_f32(
    const float* __restrict__ A, const float* __restrict__ W,
    const float* __restrict__ bias, float* __restrict__ C,
    int M, int N, int K) {
  __shared__ float As[16][68];
  __shared__ float Bs[16][68];
  const int tid = threadIdx.x;
  const int m0 = blockIdx.x * 64;
  const int n0 = blockIdx.y * 64;
  const int tx = tid & 15, ty = tid >> 4;
  const int lr = tid >> 2;
  const int lk = (tid & 3) << 2;
  float acc[4][4] = {};
  const float* Arow = A + (size_t)(m0 + lr) * K;
  const float* Wrow = W + (size_t)(n0 + lr) * K;
  for (int k0 = 0; k0 < K; k0 += 16) {
    float4 av = *(const float4*)(Arow + k0 + lk);
    float4 wv = *(const float4*)(Wrow + k0 + lk);
    __syncthreads();
    As[lk + 0][lr] = av.x; As[lk + 1][lr] = av.y;
    As[lk + 2][lr] = av.z; As[lk + 3][lr] = av.w;
    Bs[lk + 0][lr] = wv.x; Bs[lk + 1][lr] = wv.y;
    Bs[lk + 2][lr] = wv.z; Bs[lk + 3][lr] = wv.w;
    __syncthreads();
    #pragma unroll
    for (int kk = 0; kk < 16; ++kk) {
      float4 a = *(const float4*)&As[kk][ty * 4];
      float4 b = *(const float4*)&Bs[kk][tx * 4];
      acc[0][0] += a.x * b.x; acc[0][1] += a.x * b.y; acc[0][2] += a.x * b.z; acc[0][3] += a.x * b.w;
      acc[1][0] += a.y * b.x; acc[1][1] += a.y * b.y; acc[1][2] += a.y * b.z; acc[1][3] += a.y * b.w;
      acc[2][0] += a.z * b.x; acc[2][1] += a.z * b.y; acc[2][2] += a.z * b.z; acc[2][3] += a.z * b.w;
      acc[3][0] += a.w * b.x; acc[3][1] += a.w * b.y; acc[3][2] += a.w * b.z; acc[3][3] += a.w * b.w;
    }
  }
  float4 bv = *(const float4*)(bias + n0 + tx * 4);
  #pragma unroll
  for (int i = 0; i < 4; ++i) {
    int m = m0 + ty * 4 + i;
    float v0 = acc[i][0] + bv.x, v1 = acc[i][1] + bv.y;
    float v2 = acc[i][2] + bv.z, v3 = acc[i][3] + bv.w;
    if constexpr (EPI == 1) {
      v0 = gelu_f(v0); v1 = gelu_f(v1); v2 = gelu_f(v2); v3 = gelu_f(v3);
    }
    float4 ov; ov.x = v0; ov.y = v1; ov.z = v2; ov.w = v3;
    *(float4*)(C + (size_t)m * N + n0 + tx * 4) = ov;
  }
}

// ---------------------------------------------------------------------------
// mean-pool over S=4 + head LN (one wave per sample)
// ---------------------------------------------------------------------------
__global__ __launch_bounds__(256) void pool_ln_kernel(const float* __restrict__ x,
                                                      const float* __restrict__ g,
                                                      const float* __restrict__ b,
                                                      float* __restrict__ hout) {
  int bi = blockIdx.x * 4 + (threadIdx.x >> 6);
  int lane = threadIdx.x & 63;
  const float* row = x + (size_t)bi * 4 * D_;
  float vals[3];
  float sum = 0.f;
  #pragma unroll
  for (int cc = 0; cc < 3; ++cc) {
    int d = lane + cc * 64;
    float v = 0.25f * (row[d] + row[D_ + d] + row[2 * D_ + d] + row[3 * D_ + d]);
    vals[cc] = v; sum += v;
  }
  #pragma unroll
  for (int off = 1; off < 64; off <<= 1) sum += __shfl_xor(sum, off);
  float mean = sum / (float)D_;
  float vs = 0.f;
  #pragma unroll
  for (int cc = 0; cc < 3; ++cc) { float d0 = vals[cc] - mean; vs += d0 * d0; }
  #pragma unroll
  for (int off = 1; off < 64; off <<= 1) vs += __shfl_xor(vs, off);
  float rstd = rsqrtf(vs / (float)D_ + 1e-5f);
  #pragma unroll
  for (int cc = 0; cc < 3; ++cc) {
    int d = lane + cc * 64;
    hout[(size_t)bi * D_ + d] = (vals[cc] - mean) * rstd * g[d] + b[d];
  }
}

// ---------------------------------------------------------------------------
// final: out[b] = h2[b,:64] . h3_w + h3_b  (one wave per sample)
// ---------------------------------------------------------------------------
__global__ __launch_bounds__(256) void head_final_kernel(const float* __restrict__ h2,
                                                         const float* __restrict__ w,
                                                         const float* __restrict__ b,
                                                         float* __restrict__ out) {
  int bi = blockIdx.x * 4 + (threadIdx.x >> 6);
  int lane = threadIdx.x & 63;
  float v = h2[(size_t)bi * 64 + lane] * w[lane];
  #pragma unroll
  for (int off = 1; off < 64; off <<= 1) v += __shfl_xor(v, off);
  if (lane == 0) out[bi] = v + b[0];
}

// ---------------------------------------------------------------------------
extern "C" void kernel_launch(void* const* d_in, const int* in_sizes, int n_in,
                              void* d_out, int out_size, void* d_ws, size_t ws_size,
                              hipStream_t stream) {
  (void)in_sizes; (void)n_in; (void)out_size; (void)ws_size;
  const float* emb       = (const float*)d_in[0];
  const float* in_ln_w   = (const float*)d_in[1];
  const float* in_ln_b   = (const float*)d_in[2];
  const float* in_proj_w = (const float*)d_in[3];
  const float* in_proj_b = (const float*)d_in[4];
  const float* qkv_w     = (const float*)d_in[5];
  const float* qkv_b     = (const float*)d_in[6];
  const float* aow       = (const float*)d_in[7];
  const float* aob       = (const float*)d_in[8];
  const float* ln1w      = (const float*)d_in[9];
  const float* ln1b      = (const float*)d_in[10];
  const float* ln2w      = (const float*)d_in[11];
  const float* ln2b      = (const float*)d_in[12];
  const float* ff1w      = (const float*)d_in[13];
  const float* ff1b      = (const float*)d_in[14];
  const float* ff2w      = (const float*)d_in[15];
  const float* ff2b      = (const float*)d_in[16];
  const float* hlnw      = (const float*)d_in[17];
  const float* hlnb      = (const float*)d_in[18];
  const float* h1w       = (const float*)d_in[19];
  const float* h1b       = (const float*)d_in[20];
  const float* h2w       = (const float*)d_in[21];
  const float* h2b       = (const float*)d_in[22];
  const float* h3w       = (const float*)d_in[23];
  const float* h3b       = (const float*)d_in[24];
  float* out = (float*)d_out;

  float* ws = (float*)d_ws;
  size_t off = 0;
  float* x = ws + off; off += (size_t)MTOK * D_;           // fp32 residual stream
  _Float16* qf = (_Float16*)(ws + off);                    // fp16: qkv(576)/ff(768)
  off += (size_t)MTOK * FF_ / 2 + 64;
  _Float16* o = qf + (size_t)MTOK * (3 * D_);              // o in qf tail cols 576..768
  float* stE = ws + off; off += (size_t)MTOK * 2;
  float* stD = ws + off; off += (size_t)MTOK * 2;
  float* hp  = ws + off; off += (size_t)B_ * D_;
  float* h1  = ws + off; off += (size_t)B_ * 256;
  float* h2  = ws + off; off += (size_t)B_ * 64;

  // input LN stats + fused LN->in_proj->GELU->posenc; fused x-stats for ln1
  stats_e_kernel<<<MTOK, 256, 0, stream>>>(emb, stE);
  gemm_n192<false, true, 3, true><<<MTOK / 64, 256, 0, stream>>>(
      emb, in_proj_w, in_proj_b, stE, in_ln_w, in_ln_b, nullptr, x, stD, E_);

  for (int i = 0; i < NL_; ++i) {
    gemm_mfma<0><<<dim3((3 * D_) / 64, MTOK / 128), 256, 0, stream>>>(
        x, qkv_w + (size_t)i * 3 * D_ * D_, qkv_b + (size_t)i * 3 * D_, stD,
        ln1w + i * D_, ln1b + i * D_, qf, MTOK, 3 * D_, D_);
    attn_kernel<<<B_ / 4, 256, 0, stream>>>(qf, o);
    gemm_n192<true, false, 2, true><<<MTOK / 64, 256, 0, stream>>>(
        o, aow + (size_t)i * D_ * D_, aob + i * D_, nullptr, nullptr, nullptr,
        x, x, stD, D_);
    gemm_mfma<1><<<dim3(FF_ / 64, MTOK / 128), 256, 0, stream>>>(
        x, ff1w + (size_t)i * FF_ * D_, ff1b + i * FF_, stD,
        ln2w + i * D_, ln2b + i * D_, qf, MTOK, FF_, D_);
    gemm_n192<true, false, 2, true><<<MTOK / 64, 256, 0, stream>>>(
        qf, ff2w + (size_t)i * D_ * FF_, ff2b + i * D_, nullptr, nullptr, nullptr,
        x, x, stD, FF_);
  }

  pool_ln_kernel<<<B_ / 4, 256, 0, stream>>>(x, hlnw, hlnb, hp);
  gemm_f32<1><<<dim3(B_ / 64, 256 / 64), 256, 0, stream>>>(hp, h1w, h1b, h1, B_, 256, D_);
  gemm_f32<1><<<dim3(B_ / 64, 64 / 64), 256, 0, stream>>>(h1, h2w, h2b, h2, B_, 64, 256);
  head_final_kernel<<<B_ / 4, 256, 0, stream>>>(h2, h3w, h3b, out);
}

// Round 4
// 1601.374 us; speedup vs baseline: 1.8249x; 1.0052x over previous
//
#include <hip/hip_runtime.h>
#include <hip/hip_bf16.h>
#include <math.h>

#define B_   16384
#define S_   4
#define E_   1152
#define D_   192
#define H_   4
#define DH_  48
#define FF_  768
#define NL_  2
#define MTOK (B_ * S_)   // 65536 tokens

typedef __attribute__((ext_vector_type(8))) _Float16 half8;
typedef __attribute__((ext_vector_type(4))) _Float16 half4;
typedef __attribute__((ext_vector_type(4))) float floatx4;

__device__ __forceinline__ float gelu_f(float x) {
  return 0.5f * x * (1.0f + erff(x * 0.70710678118654752f));
}

// ---------------------------------------------------------------------------
// fp32 -> fp16 weight pre-pack (n % 2048 == 0)
// ---------------------------------------------------------------------------
__global__ __launch_bounds__(256) void cvt_f16_kernel(const float* __restrict__ s,
                                                      _Float16* __restrict__ d) {
  int i = (blockIdx.x * 256 + threadIdx.x) * 8;
  float4 a = *(const float4*)(s + i);
  float4 b = *(const float4*)(s + i + 4);
  half8 h;
  h[0] = (_Float16)a.x; h[1] = (_Float16)a.y; h[2] = (_Float16)a.z; h[3] = (_Float16)a.w;
  h[4] = (_Float16)b.x; h[5] = (_Float16)b.y; h[6] = (_Float16)b.z; h[7] = (_Float16)b.w;
  *(half8*)(d + i) = h;
}

// ---------------------------------------------------------------------------
// Small-K GEMM (K=192): C_f16[M,N] = epi(LN(A)[M,192] @ Wh[N,192]^T + bias)
// BM=64; LN'd fp16 A-tile staged in LDS ONCE (A read exactly once from HBM,
// LN+cvt done once), then N looped in 64-col chunks of preconverted fp16 W.
// 4 waves in 2x2; each wave 32x32 of the chunk via 2x2 16x16x32 MFMA, kk=6.
// EPI: 0=bias (qkv), 1=bias+GELU (ff1).
// ---------------------------------------------------------------------------
template <int EPI>
__global__ __launch_bounds__(256) void gemm_smallk(
    const float* __restrict__ A, const _Float16* __restrict__ Wh,
    const float* __restrict__ bias, const float* __restrict__ stats,
    const float* __restrict__ lng, const float* __restrict__ lnb,
    _Float16* __restrict__ C, int N) {
  __shared__ __align__(16) _Float16 Ah[64][200];  // 400 B stride: /4 % 32 == 4
  __shared__ __align__(16) _Float16 Wc[64][200];
  const int tid = threadIdx.x;
  const int m0 = blockIdx.x * 64;
  const int ra = tid >> 2, ca = (tid & 3) * 48;   // A/W staging: 48 elems/thread
  const int w = tid >> 6, lane = tid & 63;
  const int ln16 = lane & 15, quad = lane >> 4;
  const int wm = (w >> 1) * 32, wn = (w & 1) * 32;

  // ---- stage LN(A) once ----
  {
    const float sm  = stats[2 * (m0 + ra)];
    const float srs = stats[2 * (m0 + ra) + 1];
    const float* Ar = A + (size_t)(m0 + ra) * 192 + ca;
    #pragma unroll
    for (int j = 0; j < 6; ++j) {
      float4 a0 = *(const float4*)(Ar + j * 8);
      float4 a1 = *(const float4*)(Ar + j * 8 + 4);
      float4 g0 = *(const float4*)(lng + ca + j * 8);
      float4 g1 = *(const float4*)(lng + ca + j * 8 + 4);
      float4 b0 = *(const float4*)(lnb + ca + j * 8);
      float4 b1 = *(const float4*)(lnb + ca + j * 8 + 4);
      half8 h;
      h[0] = (_Float16)((a0.x - sm) * srs * g0.x + b0.x);
      h[1] = (_Float16)((a0.y - sm) * srs * g0.y + b0.y);
      h[2] = (_Float16)((a0.z - sm) * srs * g0.z + b0.z);
      h[3] = (_Float16)((a0.w - sm) * srs * g0.w + b0.w);
      h[4] = (_Float16)((a1.x - sm) * srs * g1.x + b1.x);
      h[5] = (_Float16)((a1.y - sm) * srs * g1.y + b1.y);
      h[6] = (_Float16)((a1.z - sm) * srs * g1.z + b1.z);
      h[7] = (_Float16)((a1.w - sm) * srs * g1.w + b1.w);
      *(half8*)&Ah[ra][ca + j * 8] = h;
    }
  }

  const int nch = N >> 6;
  for (int nc = 0; nc < nch; ++nc) {
    // prefetch W chunk into regs before the barrier
    uint4 u[6];
    const uint4* wp = (const uint4*)(Wh + (size_t)(nc * 64 + ra) * 192 + ca);
    #pragma unroll
    for (int j = 0; j < 6; ++j) u[j] = wp[j];
    __syncthreads();   // Ah ready (first iter) / previous chunk's reads done
    #pragma unroll
    for (int j = 0; j < 6; ++j) *(uint4*)&Wc[ra][ca + j * 8] = u[j];
    __syncthreads();

    floatx4 acc[2][2] = {};
    #pragma unroll
    for (int kk = 0; kk < 6; ++kk) {
      half8 af[2], bf[2];
      #pragma unroll
      for (int mt = 0; mt < 2; ++mt)
        af[mt] = *(const half8*)&Ah[wm + mt * 16 + ln16][kk * 32 + quad * 8];
      #pragma unroll
      for (int nt = 0; nt < 2; ++nt)
        bf[nt] = *(const half8*)&Wc[wn + nt * 16 + ln16][kk * 32 + quad * 8];
      #pragma unroll
      for (int mt = 0; mt < 2; ++mt)
        #pragma unroll
        for (int nt = 0; nt < 2; ++nt)
          acc[mt][nt] = __builtin_amdgcn_mfma_f32_16x16x32_f16(
              af[mt], bf[nt], acc[mt][nt], 0, 0, 0);
    }
    #pragma unroll
    for (int nt = 0; nt < 2; ++nt) {
      const int col = nc * 64 + wn + nt * 16 + ln16;
      const float bv = bias[col];
      #pragma unroll
      for (int mt = 0; mt < 2; ++mt) {
        #pragma unroll
        for (int r = 0; r < 4; ++r) {
          const int row = m0 + wm + mt * 16 + quad * 4 + r;
          float v = acc[mt][nt][r] + bv;
          if constexpr (EPI == 1) v = gelu_f(v);
          C[(size_t)row * N + col] = (_Float16)v;
        }
      }
    }
  }
}

// ---------------------------------------------------------------------------
// Full-N MFMA GEMM for N=192 outputs: C[M,192] = epi(op(A)[M,K] @ Wh[192,K]^T)
// One block owns 64 complete output rows; W is preconverted fp16.
// PRESTATS: compute per-row LN stats from global A inside the kernel (row pass
//   hits L2/L3 on the staging re-read) — used by in_proj (A=emb, K=1152).
// A_F16: A fp16 (attn_out o / ff2 qf). LN_A: LN on fp32 A (in_proj).
// EPI: 2 = bias+residual(fp32, aliases C); 3 = bias+GELU+posenc.
// STATS: fused per-row mean/rstd of the OUTPUT into stats_out.
// ---------------------------------------------------------------------------
template <bool A_F16, bool LN_A, int EPI, bool STATS, bool PRESTATS>
__global__ __launch_bounds__(256) void gemm_n192(
    const void* __restrict__ A_, const _Float16* __restrict__ Wh,
    const float* __restrict__ bias, const float* __restrict__ stats_in,
    const float* __restrict__ lng, const float* __restrict__ lnb,
    const float* __restrict__ res, float* __restrict__ C,
    float* __restrict__ stats_out, int K) {
  __shared__ __align__(16) _Float16 As[64][72];
  __shared__ __align__(16) _Float16 Bs[192][72];
  __shared__ float red[4][64][2];
  const int tid = threadIdx.x;
  const int m0 = blockIdx.x * 64;
  const int r_a = tid >> 2;           // 0..63 (A row; also base B row)
  const int c_a = (tid & 3) * 16;     // element offset within BK=64
  const int w = tid >> 6, lane = tid & 63;
  const int ln16 = lane & 15, quad = lane >> 4;
  const int wn = w * 48;

  floatx4 acc[4][3] = {};
  float sm = 0.f, srs = 0.f;
  const float*    ArowF = (const float*)A_ + (size_t)(m0 + r_a) * K;
  const _Float16* ArowH = (const _Float16*)A_ + (size_t)(m0 + r_a) * K;
  if constexpr (PRESTATS) {
    float s = 0.f, q = 0.f;
    for (int c = (tid & 3) * 4; c < K; c += 16) {
      float4 v = *(const float4*)(ArowF + c);
      s += v.x + v.y + v.z + v.w;
      q += v.x * v.x + v.y * v.y + v.z * v.z + v.w * v.w;
    }
    s += __shfl_xor(s, 1); s += __shfl_xor(s, 2);
    q += __shfl_xor(q, 1); q += __shfl_xor(q, 2);
    float mean = s / (float)K;
    sm = mean;
    srs = rsqrtf(q / (float)K - mean * mean + 1e-5f);
  } else if constexpr (LN_A) {
    sm  = stats_in[2 * (m0 + r_a)];
    srs = stats_in[2 * (m0 + r_a) + 1];
  }

  for (int k0 = 0; k0 < K; k0 += 64) {
    // ---- A (16 halfs / thread) ----
    uint4 uA[2];
    half8 hA[2];
    if constexpr (A_F16) {
      const uint4* p = (const uint4*)(ArowH + k0 + c_a);
      uA[0] = p[0]; uA[1] = p[1];
    } else {
      float4 a[4];
      #pragma unroll
      for (int j = 0; j < 4; ++j) a[j] = *(const float4*)(ArowF + k0 + c_a + j * 4);
      if constexpr (LN_A) {
        #pragma unroll
        for (int j = 0; j < 4; ++j) {
          float4 g  = *(const float4*)(lng + k0 + c_a + j * 4);
          float4 bb = *(const float4*)(lnb + k0 + c_a + j * 4);
          a[j].x = (a[j].x - sm) * srs * g.x + bb.x;
          a[j].y = (a[j].y - sm) * srs * g.y + bb.y;
          a[j].z = (a[j].z - sm) * srs * g.z + bb.z;
          a[j].w = (a[j].w - sm) * srs * g.w + bb.w;
        }
      }
      #pragma unroll
      for (int j = 0; j < 2; ++j) {
        half8 h;
        h[0] = (_Float16)a[2*j].x;   h[1] = (_Float16)a[2*j].y;
        h[2] = (_Float16)a[2*j].z;   h[3] = (_Float16)a[2*j].w;
        h[4] = (_Float16)a[2*j+1].x; h[5] = (_Float16)a[2*j+1].y;
        h[6] = (_Float16)a[2*j+1].z; h[7] = (_Float16)a[2*j+1].w;
        hA[j] = h;
      }
    }
    // ---- B: rows r_a, r_a+64, r_a+128 from fp16 W (L2-resident) ----
    uint4 uB[3][2];
    #pragma unroll
    for (int i = 0; i < 3; ++i) {
      const uint4* wp = (const uint4*)(Wh + (size_t)(r_a + i * 64) * K + k0 + c_a);
      uB[i][0] = wp[0]; uB[i][1] = wp[1];
    }
    __syncthreads();
    if constexpr (A_F16) {
      *(uint4*)&As[r_a][c_a]     = uA[0];
      *(uint4*)&As[r_a][c_a + 8] = uA[1];
    } else {
      *(half8*)&As[r_a][c_a]     = hA[0];
      *(half8*)&As[r_a][c_a + 8] = hA[1];
    }
    #pragma unroll
    for (int i = 0; i < 3; ++i) {
      *(uint4*)&Bs[r_a + i * 64][c_a]     = uB[i][0];
      *(uint4*)&Bs[r_a + i * 64][c_a + 8] = uB[i][1];
    }
    __syncthreads();
    #pragma unroll
    for (int kk = 0; kk < 64; kk += 32) {
      half8 af[4], bf[3];
      #pragma unroll
      for (int mt = 0; mt < 4; ++mt)
        af[mt] = *(const half8*)&As[mt * 16 + ln16][kk + quad * 8];
      #pragma unroll
      for (int nt = 0; nt < 3; ++nt)
        bf[nt] = *(const half8*)&Bs[wn + nt * 16 + ln16][kk + quad * 8];
      #pragma unroll
      for (int mt = 0; mt < 4; ++mt)
        #pragma unroll
        for (int nt = 0; nt < 3; ++nt)
          acc[mt][nt] = __builtin_amdgcn_mfma_f32_16x16x32_f16(
              af[mt], bf[nt], acc[mt][nt], 0, 0, 0);
    }
  }

  // ---- epilogue ----
  float bv[3], pe_val[3][4];
  #pragma unroll
  for (int nt = 0; nt < 3; ++nt) {
    int col = wn + nt * 16 + ln16;
    bv[nt] = bias[col];
    if constexpr (EPI == 3) {
      float divv = expf((float)(col & ~1) * (-0.047970522770709292f));
      bool odd = (col & 1) != 0;
      #pragma unroll
      for (int r = 0; r < 4; ++r) {
        float ang = (float)r * divv;
        pe_val[nt][r] = odd ? cosf(ang) : sinf(ang);
      }
    }
  }
  #pragma unroll
  for (int mt = 0; mt < 4; ++mt) {
    #pragma unroll
    for (int r = 0; r < 4; ++r) {
      const int row = m0 + mt * 16 + quad * 4 + r;  // row & 3 == r
      float s = 0.f, q = 0.f;
      #pragma unroll
      for (int nt = 0; nt < 3; ++nt) {
        const int col = wn + nt * 16 + ln16;
        float v = acc[mt][nt][r] + bv[nt];
        if constexpr (EPI == 3) { v = gelu_f(v); v += pe_val[nt][r]; }
        if constexpr (EPI == 2) v += res[(size_t)row * D_ + col];
        C[(size_t)row * D_ + col] = v;
        if constexpr (STATS) { s += v; q += v * v; }
      }
      if constexpr (STATS) {
        #pragma unroll
        for (int off = 1; off < 16; off <<= 1) {
          s += __shfl_xor(s, off);
          q += __shfl_xor(q, off);
        }
        if (ln16 == 0) {
          red[w][mt * 16 + quad * 4 + r][0] = s;
          red[w][mt * 16 + quad * 4 + r][1] = q;
        }
      }
    }
  }
  if constexpr (STATS) {
    __syncthreads();
    if (tid < 64) {
      float s = red[0][tid][0] + red[1][tid][0] + red[2][tid][0] + red[3][tid][0];
      float q = red[0][tid][1] + red[1][tid][1] + red[2][tid][1] + red[3][tid][1];
      float mean = s * (1.f / 192.f);
      float var  = q * (1.f / 192.f) - mean * mean;
      stats_out[2 * (m0 + tid)]     = mean;
      stats_out[2 * (m0 + tid) + 1] = rsqrtf(var + 1e-5f);
    }
  }
}

// ---------------------------------------------------------------------------
// Attention: S=4, H=4, DH=48. 4 samples per block, one wave per sample.
// qkv (fp16) row layout per token: [q(192) | k(192) | v(192)].
// ---------------------------------------------------------------------------
__global__ __launch_bounds__(256) void attn_kernel(const _Float16* __restrict__ qkv,
                                                   _Float16* __restrict__ o) {
  __shared__ float sq[4][4][576];
  __shared__ float sp[4][4][4][4];
  int tid = threadIdx.x;
  int b0 = blockIdx.x * 4;
  const _Float16* src = qkv + (size_t)b0 * 4 * 576;
  float* dst = &sq[0][0][0];
  #pragma unroll
  for (int t = 0; t < 9; ++t) {
    int i = (tid + t * 256) * 4;
    half4 hv = *(const half4*)(src + i);
    dst[i + 0] = (float)hv[0]; dst[i + 1] = (float)hv[1];
    dst[i + 2] = (float)hv[2]; dst[i + 3] = (float)hv[3];
  }
  __syncthreads();
  int sg = tid >> 6;
  int lane = tid & 63;
  int h = lane >> 4, i = (lane >> 2) & 3, j = lane & 3;
  const float* qp = &sq[sg][i][h * 48];
  const float* kp = &sq[sg][j][192 + h * 48];
  float s = 0.f;
  #pragma unroll
  for (int d = 0; d < 48; ++d) s += qp[d] * kp[d];
  s *= 0.14433756729740643f;  // 1/sqrt(48)
  float mx = fmaxf(s, __shfl_xor(s, 1));
  mx = fmaxf(mx, __shfl_xor(mx, 2));
  float e = expf(s - mx);
  float sum = e + __shfl_xor(e, 1);
  sum += __shfl_xor(sum, 2);
  sp[sg][h][i][j] = e / sum;
  __syncthreads();
  #pragma unroll
  for (int ii = 0; ii < 4; ++ii) {
    #pragma unroll
    for (int cc = 0; cc < 3; ++cc) {
      int c = lane + cc * 64;
      int hh = c / 48;
      float acc = 0.f;
      #pragma unroll
      for (int jj = 0; jj < 4; ++jj)
        acc += sp[sg][hh][ii][jj] * sq[sg][jj][384 + c];
      o[((size_t)(b0 + sg) * 4 + ii) * D_ + c] = (_Float16)acc;
    }
  }
}

// ---------------------------------------------------------------------------
// fp32 GEMM (head only): C[M,N] = epi(A[M,K] @ W[N,K]^T + bias)
// ---------------------------------------------------------------------------
template <int EPI>
__global__ __launch_bounds__(256) void gemm_f32(
    const float* __restrict__ A, const float* __restrict__ W,
    const float* __restrict__ bias, float* __restrict__ C,
    int M, int N, int K) {
  __shared__ float As[16][68];
  __shared__ float Bs[16][68];
  const int tid = threadIdx.x;
  const int m0 = blockIdx.x * 64;
  const int n0 = blockIdx.y * 64;
  const int tx = tid & 15, ty = tid >> 4;
  const int lr = tid >> 2;
  const int lk = (tid & 3) << 2;
  float acc[4][4] = {};
  const float* Arow = A + (size_t)(m0 + lr) * K;
  const float* Wrow = W + (size_t)(n0 + lr) * K;
  for (int k0 = 0; k0 < K; k0 += 16) {
    float4 av = *(const float4*)(Arow + k0 + lk);
    float4 wv = *(const float4*)(Wrow + k0 + lk);
    __syncthreads();
    As[lk + 0][lr] = av.x; As[lk + 1][lr] = av.y;
    As[lk + 2][lr] = av.z; As[lk + 3][lr] = av.w;
    Bs[lk + 0][lr] = wv.x; Bs[lk + 1][lr] = wv.y;
    Bs[lk + 2][lr] = wv.z; Bs[lk + 3][lr] = wv.w;
    __syncthreads();
    #pragma unroll
    for (int kk = 0; kk < 16; ++kk) {
      float4 a = *(const float4*)&As[kk][ty * 4];
      float4 b = *(const float4*)&Bs[kk][tx * 4];
      acc[0][0] += a.x * b.x; acc[0][1] += a.x * b.y; acc[0][2] += a.x * b.z; acc[0][3] += a.x * b.w;
      acc[1][0] += a.y * b.x; acc[1][1] += a.y * b.y; acc[1][2] += a.y * b.z; acc[1][3] += a.y * b.w;
      acc[2][0] += a.z * b.x; acc[2][1] += a.z * b.y; acc[2][2] += a.z * b.z; acc[2][3] += a.z * b.w;
      acc[3][0] += a.w * b.x; acc[3][1] += a.w * b.y; acc[3][2] += a.w * b.z; acc[3][3] += a.w * b.w;
    }
  }
  float4 bv = *(const float4*)(bias + n0 + tx * 4);
  #pragma unroll
  for (int i = 0; i < 4; ++i) {
    int m = m0 + ty * 4 + i;
    float v0 = acc[i][0] + bv.x, v1 = acc[i][1] + bv.y;
    float v2 = acc[i][2] + bv.z, v3 = acc[i][3] + bv.w;
    if constexpr (EPI == 1) {
      v0 = gelu_f(v0); v1 = gelu_f(v1); v2 = gelu_f(v2); v3 = gelu_f(v3);
    }
    float4 ov; ov.x = v0; ov.y = v1; ov.z = v2; ov.w = v3;
    *(float4*)(C + (size_t)m * N + n0 + tx * 4) = ov;
  }
}

// ---------------------------------------------------------------------------
// mean-pool over S=4 + head LN (one wave per sample)
// ---------------------------------------------------------------------------
__global__ __launch_bounds__(256) void pool_ln_kernel(const float* __restrict__ x,
                                                      const float* __restrict__ g,
                                                      const float* __restrict__ b,
                                                      float* __restrict__ hout) {
  int bi = blockIdx.x * 4 + (threadIdx.x >> 6);
  int lane = threadIdx.x & 63;
  const float* row = x + (size_t)bi * 4 * D_;
  float vals[3];
  float sum = 0.f;
  #pragma unroll
  for (int cc = 0; cc < 3; ++cc) {
    int d = lane + cc * 64;
    float v = 0.25f * (row[d] + row[D_ + d] + row[2 * D_ + d] + row[3 * D_ + d]);
    vals[cc] = v; sum += v;
  }
  #pragma unroll
  for (int off = 1; off < 64; off <<= 1) sum += __shfl_xor(sum, off);
  float mean = sum / (float)D_;
  float vs = 0.f;
  #pragma unroll
  for (int cc = 0; cc < 3; ++cc) { float d0 = vals[cc] - mean; vs += d0 * d0; }
  #pragma unroll
  for (int off = 1; off < 64; off <<= 1) vs += __shfl_xor(vs, off);
  float rstd = rsqrtf(vs / (float)D_ + 1e-5f);
  #pragma unroll
  for (int cc = 0; cc < 3; ++cc) {
    int d = lane + cc * 64;
    hout[(size_t)bi * D_ + d] = (vals[cc] - mean) * rstd * g[d] + b[d];
  }
}

// ---------------------------------------------------------------------------
// final: out[b] = h2[b,:64] . h3_w + h3_b  (one wave per sample)
// ---------------------------------------------------------------------------
__global__ __launch_bounds__(256) void head_final_kernel(const float* __restrict__ h2,
                                                         const float* __restrict__ w,
                                                         const float* __restrict__ b,
                                                         float* __restrict__ out) {
  int bi = blockIdx.x * 4 + (threadIdx.x >> 6);
  int lane = threadIdx.x & 63;
  float v = h2[(size_t)bi * 64 + lane] * w[lane];
  #pragma unroll
  for (int off = 1; off < 64; off <<= 1) v += __shfl_xor(v, off);
  if (lane == 0) out[bi] = v + b[0];
}

// ---------------------------------------------------------------------------
extern "C" void kernel_launch(void* const* d_in, const int* in_sizes, int n_in,
                              void* d_out, int out_size, void* d_ws, size_t ws_size,
                              hipStream_t stream) {
  (void)in_sizes; (void)n_in; (void)out_size; (void)ws_size;
  const float* emb       = (const float*)d_in[0];
  const float* in_ln_w   = (const float*)d_in[1];
  const float* in_ln_b   = (const float*)d_in[2];
  const float* in_proj_w = (const float*)d_in[3];
  const float* in_proj_b = (const float*)d_in[4];
  const float* qkv_w     = (const float*)d_in[5];
  const float* qkv_b     = (const float*)d_in[6];
  const float* aow       = (const float*)d_in[7];
  const float* aob       = (const float*)d_in[8];
  const float* ln1w      = (const float*)d_in[9];
  const float* ln1b      = (const float*)d_in[10];
  const float* ln2w      = (const float*)d_in[11];
  const float* ln2b      = (const float*)d_in[12];
  const float* ff1w      = (const float*)d_in[13];
  const float* ff1b      = (const float*)d_in[14];
  const float* ff2w      = (const float*)d_in[15];
  const float* ff2b      = (const float*)d_in[16];
  const float* hlnw      = (const float*)d_in[17];
  const float* hlnb      = (const float*)d_in[18];
  const float* h1w       = (const float*)d_in[19];
  const float* h1b       = (const float*)d_in[20];
  const float* h2w       = (const float*)d_in[21];
  const float* h2b       = (const float*)d_in[22];
  const float* h3w       = (const float*)d_in[23];
  const float* h3b       = (const float*)d_in[24];
  float* out = (float*)d_out;

  float* ws = (float*)d_ws;
  size_t off = 0;
  float* x = ws + off; off += (size_t)MTOK * D_;           // fp32 residual stream
  _Float16* qf = (_Float16*)(ws + off);                    // fp16: qkv(576)/ff(768)
  off += (size_t)MTOK * FF_ / 2 + 64;
  _Float16* o = qf + (size_t)MTOK * (3 * D_);              // o in qf tail cols 576..768
  float* stD = ws + off; off += (size_t)MTOK * 2;
  float* hp  = ws + off; off += (size_t)B_ * D_;
  float* h1  = ws + off; off += (size_t)B_ * 256;
  float* h2  = ws + off; off += (size_t)B_ * 64;
  // fp16 weight pack region
  _Float16* wh = (_Float16*)(ws + off);
  _Float16* w_inproj = wh;                       // 192*1152        = 221184
  _Float16* w_qkv    = w_inproj + 221184;        // 2*576*192       = 221184
  _Float16* w_ao     = w_qkv    + 221184;        // 2*192*192       =  73728
  _Float16* w_ff1    = w_ao     + 73728;         // 2*768*192       = 294912
  _Float16* w_ff2    = w_ff1    + 294912;        // 2*192*768       = 294912

  // ---- pre-pack weights to fp16 ----
  cvt_f16_kernel<<<221184 / 2048, 256, 0, stream>>>(in_proj_w, w_inproj);
  cvt_f16_kernel<<<221184 / 2048, 256, 0, stream>>>(qkv_w, w_qkv);
  cvt_f16_kernel<<<73728  / 2048, 256, 0, stream>>>(aow, w_ao);
  cvt_f16_kernel<<<294912 / 2048, 256, 0, stream>>>(ff1w, w_ff1);
  cvt_f16_kernel<<<294912 / 2048, 256, 0, stream>>>(ff2w, w_ff2);

  // in_proj with inline emb-LN stats + fused output stats for ln1
  gemm_n192<false, true, 3, true, true><<<MTOK / 64, 256, 0, stream>>>(
      emb, w_inproj, in_proj_b, nullptr, in_ln_w, in_ln_b, nullptr, x, stD, E_);

  for (int i = 0; i < NL_; ++i) {
    gemm_smallk<0><<<MTOK / 64, 256, 0, stream>>>(
        x, w_qkv + (size_t)i * 110592, qkv_b + (size_t)i * 3 * D_, stD,
        ln1w + i * D_, ln1b + i * D_, qf, 3 * D_);
    attn_kernel<<<B_ / 4, 256, 0, stream>>>(qf, o);
    gemm_n192<true, false, 2, true, false><<<MTOK / 64, 256, 0, stream>>>(
        o, w_ao + (size_t)i * 36864, aob + i * D_, nullptr, nullptr, nullptr,
        x, x, stD, D_);
    gemm_smallk<1><<<MTOK / 64, 256, 0, stream>>>(
        x, w_ff1 + (size_t)i * 147456, ff1b + i * FF_, stD,
        ln2w + i * D_, ln2b + i * D_, qf, FF_);
    gemm_n192<true, false, 2, true, false><<<MTOK / 64, 256, 0, stream>>>(
        qf, w_ff2 + (size_t)i * 147456, ff2b + i * D_, nullptr, nullptr, nullptr,
        x, x, stD, FF_);
  }

  pool_ln_kernel<<<B_ / 4, 256, 0, stream>>>(x, hlnw, hlnb, hp);
  gemm_f32<1><<<dim3(B_ / 64, 256 / 64), 256, 0, stream>>>(hp, h1w, h1b, h1, B_, 256, D_);
  gemm_f32<1><<<dim3(B_ / 64, 64 / 64), 256, 0, stream>>>(h1, h2w, h2b, h2, B_, 64, 256);
  head_final_kernel<<<B_ / 4, 256, 0, stream>>>(h2, h3w, h3b, out);
}

// Round 5
// 1494.296 us; speedup vs baseline: 1.9557x; 1.0717x over previous
//
#include <hip/hip_runtime.h>
#include <hip/hip_bf16.h>
#include <math.h>

#define B_   16384
#define S_   4
#define E_   1152
#define D_   192
#define FF_  768
#define NL_  2
#define MTOK (B_ * S_)   // 65536 tokens

typedef __attribute__((ext_vector_type(8))) _Float16 half8;
typedef __attribute__((ext_vector_type(4))) float floatx4;

__device__ __forceinline__ float gelu_f(float x) {
  return 0.5f * x * (1.0f + erff(x * 0.70710678118654752f));
}

// ---------------------------------------------------------------------------
// fp32 -> fp16 weight pre-pack (n % 2048 == 0)
// ---------------------------------------------------------------------------
__global__ __launch_bounds__(256) void cvt_f16_kernel(const float* __restrict__ s,
                                                      _Float16* __restrict__ d) {
  int i = (blockIdx.x * 256 + threadIdx.x) * 8;
  float4 a = *(const float4*)(s + i);
  float4 b = *(const float4*)(s + i + 4);
  half8 h;
  h[0] = (_Float16)a.x; h[1] = (_Float16)a.y; h[2] = (_Float16)a.z; h[3] = (_Float16)a.w;
  h[4] = (_Float16)b.x; h[5] = (_Float16)b.y; h[6] = (_Float16)b.z; h[7] = (_Float16)b.w;
  *(half8*)(d + i) = h;
}

// ---------------------------------------------------------------------------
// in_proj: x[M,192] = posenc(GELU(LN(emb)[M,1152] @ Wh[192,1152]^T + bias))
// BM=64. Fused inline emb-LN stats (row pass; staging re-read hits cache),
// register-prefetch pipelined k-loop, LDS-staged coalesced fp32 output with
// fused output LN-stats (for layer-0 LN1) via shuffle during copy-out.
// ---------------------------------------------------------------------------
__global__ __launch_bounds__(256) void inproj_kernel(
    const float* __restrict__ emb, const _Float16* __restrict__ wh,
    const float* __restrict__ bias, const float* __restrict__ lng,
    const float* __restrict__ lnb, float* __restrict__ xout,
    float* __restrict__ stD) {
  __shared__ __align__(16) char pool[49152];   // As(9216)+Bs(27648) | outs(49152)
  _Float16 (*As)[72] = (_Float16 (*)[72])pool;
  _Float16 (*Bs)[72] = (_Float16 (*)[72])(pool + 9216);
  float* outs = (float*)pool;
  const int tid = threadIdx.x;
  const int m0 = blockIdx.x * 64;
  const int r_a = tid >> 2;           // 0..63
  const int c_a = (tid & 3) * 16;     // 0/16/32/48 within BK=64
  const int w = tid >> 6, lane = tid & 63;
  const int ln16 = lane & 15, quad = lane >> 4;
  const int wn = w * 48;

  const float* Arow = emb + (size_t)(m0 + r_a) * 1152;
  // inline LN stats of emb row (4 threads per row)
  float sm, srs;
  {
    float s = 0.f, q = 0.f;
    for (int c = (tid & 3) * 4; c < 1152; c += 16) {
      float4 v = *(const float4*)(Arow + c);
      s += v.x + v.y + v.z + v.w;
      q += v.x * v.x + v.y * v.y + v.z * v.z + v.w * v.w;
    }
    s += __shfl_xor(s, 1); s += __shfl_xor(s, 2);
    q += __shfl_xor(q, 1); q += __shfl_xor(q, 2);
    sm = s * (1.f / 1152.f);
    srs = rsqrtf(q * (1.f / 1152.f) - sm * sm + 1e-5f);
  }

  floatx4 acc[4][3] = {};
  float4 pa[4];
  uint4 pb[3][2];
  auto loadAB = [&](int k0) {
    #pragma unroll
    for (int j = 0; j < 4; ++j) pa[j] = *(const float4*)(Arow + k0 + c_a + j * 4);
    #pragma unroll
    for (int i2 = 0; i2 < 3; ++i2) {
      const uint4* wp = (const uint4*)(wh + (size_t)(r_a + i2 * 64) * 1152 + k0 + c_a);
      pb[i2][0] = wp[0]; pb[i2][1] = wp[1];
    }
  };
  loadAB(0);
  for (int k0 = 0; k0 < 1152; k0 += 64) {
    __syncthreads();
    #pragma unroll
    for (int j = 0; j < 2; ++j) {
      float4 a0 = pa[2 * j], a1 = pa[2 * j + 1];
      float4 g0 = *(const float4*)(lng + k0 + c_a + j * 8);
      float4 g1 = *(const float4*)(lng + k0 + c_a + j * 8 + 4);
      float4 b0 = *(const float4*)(lnb + k0 + c_a + j * 8);
      float4 b1 = *(const float4*)(lnb + k0 + c_a + j * 8 + 4);
      half8 h;
      h[0] = (_Float16)((a0.x - sm) * srs * g0.x + b0.x);
      h[1] = (_Float16)((a0.y - sm) * srs * g0.y + b0.y);
      h[2] = (_Float16)((a0.z - sm) * srs * g0.z + b0.z);
      h[3] = (_Float16)((a0.w - sm) * srs * g0.w + b0.w);
      h[4] = (_Float16)((a1.x - sm) * srs * g1.x + b1.x);
      h[5] = (_Float16)((a1.y - sm) * srs * g1.y + b1.y);
      h[6] = (_Float16)((a1.z - sm) * srs * g1.z + b1.z);
      h[7] = (_Float16)((a1.w - sm) * srs * g1.w + b1.w);
      *(half8*)&As[r_a][c_a + j * 8] = h;
    }
    #pragma unroll
    for (int i2 = 0; i2 < 3; ++i2) {
      *(uint4*)&Bs[r_a + i2 * 64][c_a]     = pb[i2][0];
      *(uint4*)&Bs[r_a + i2 * 64][c_a + 8] = pb[i2][1];
    }
    __syncthreads();
    if (k0 + 64 < 1152) loadAB(k0 + 64);   // prefetch overlaps MFMA below
    #pragma unroll
    for (int kk = 0; kk < 64; kk += 32) {
      half8 af[4], bf[3];
      #pragma unroll
      for (int mt = 0; mt < 4; ++mt)
        af[mt] = *(const half8*)&As[mt * 16 + ln16][kk + quad * 8];
      #pragma unroll
      for (int nt = 0; nt < 3; ++nt)
        bf[nt] = *(const half8*)&Bs[wn + nt * 16 + ln16][kk + quad * 8];
      #pragma unroll
      for (int mt = 0; mt < 4; ++mt)
        #pragma unroll
        for (int nt = 0; nt < 3; ++nt)
          acc[mt][nt] = __builtin_amdgcn_mfma_f32_16x16x32_f16(
              af[mt], bf[nt], acc[mt][nt], 0, 0, 0);
    }
  }
  __syncthreads();   // MFMA reads of As/Bs done; reuse pool as outs

  // epilogue -> LDS stage (bias + GELU + posenc)
  #pragma unroll
  for (int nt = 0; nt < 3; ++nt) {
    const int col = wn + nt * 16 + ln16;
    const float bv = bias[col];
    const float divv = expf((float)(col & ~1) * (-0.047970522770709292f));
    const bool odd = (col & 1) != 0;
    #pragma unroll
    for (int mt = 0; mt < 4; ++mt) {
      #pragma unroll
      for (int r = 0; r < 4; ++r) {
        const int row = mt * 16 + quad * 4 + r;   // global row = m0+row, row&3 == r
        float v = gelu_f(acc[mt][nt][r] + bv);
        float ang = (float)r * divv;
        v += odd ? cosf(ang) : sinf(ang);
        outs[row * 192 + col] = v;
      }
    }
  }
  __syncthreads();
  // coalesced copy-out + fused output LN stats (4 threads per row)
  {
    const int fbase = tid * 12;       // float4 index; row = tid/4
    const int row = tid >> 2;
    float* xg = xout + (size_t)m0 * 192;
    float s = 0.f, q = 0.f;
    #pragma unroll
    for (int j = 0; j < 12; ++j) {
      float4 v = ((const float4*)outs)[fbase + j];
      s += v.x + v.y + v.z + v.w;
      q += v.x * v.x + v.y * v.y + v.z * v.z + v.w * v.w;
      *(float4*)(xg + (fbase + j) * 4) = v;
    }
    s += __shfl_xor(s, 1); s += __shfl_xor(s, 2);
    q += __shfl_xor(q, 1); q += __shfl_xor(q, 2);
    if ((tid & 3) == 0) {
      float mean = s * (1.f / 192.f);
      stD[2 * (m0 + row)] = mean;
      stD[2 * (m0 + row) + 1] = rsqrtf(q * (1.f / 192.f) - mean * mean + 1e-5f);
    }
  }
}

// ---------------------------------------------------------------------------
// Fused attention block (per layer): x += attn_out(attn(qkv(LN1(x))))
// BM=32 tokens = 8 samples/block. B-fragments loaded directly global->reg
// from fp16 W[n][k] (lane(ln16,quad) reads W[n0+ln16][quad*8..+8] = the MFMA
// B operand exactly). qkv + o never touch HBM. Writes LN2 stats into stD.
// ---------------------------------------------------------------------------
__global__ __launch_bounds__(256) void layer_attn_kernel(
    float* __restrict__ x, const _Float16* __restrict__ wqkv,
    const float* __restrict__ bqkv, const _Float16* __restrict__ wao,
    const float* __restrict__ bao, const float* __restrict__ ln1g,
    const float* __restrict__ ln1b_, float* __restrict__ stD) {
  __shared__ __align__(16) _Float16 xh[32][200];   // LN1(x), then o
  __shared__ __align__(16) _Float16 qk[32][584];   // qkv, then fp32 out stage
  __shared__ float sp[8][4][4][4];
  const int tid = threadIdx.x;
  const int m0 = blockIdx.x * 32;
  const int w = tid >> 6, lane = tid & 63;
  const int ln16 = lane & 15, quad = lane >> 4;

  // phase 0: LN1(x) -> xh (8 threads per row, 24 floats each)
  {
    const int ra = tid >> 3, ca = (tid & 7) * 24;
    const float sm = stD[2 * (m0 + ra)], srs = stD[2 * (m0 + ra) + 1];
    const float* Ar = x + (size_t)(m0 + ra) * 192 + ca;
    #pragma unroll
    for (int j = 0; j < 3; ++j) {
      float4 a0 = *(const float4*)(Ar + j * 8);
      float4 a1 = *(const float4*)(Ar + j * 8 + 4);
      float4 g0 = *(const float4*)(ln1g + ca + j * 8);
      float4 g1 = *(const float4*)(ln1g + ca + j * 8 + 4);
      float4 b0 = *(const float4*)(ln1b_ + ca + j * 8);
      float4 b1 = *(const float4*)(ln1b_ + ca + j * 8 + 4);
      half8 h;
      h[0] = (_Float16)((a0.x - sm) * srs * g0.x + b0.x);
      h[1] = (_Float16)((a0.y - sm) * srs * g0.y + b0.y);
      h[2] = (_Float16)((a0.z - sm) * srs * g0.z + b0.z);
      h[3] = (_Float16)((a0.w - sm) * srs * g0.w + b0.w);
      h[4] = (_Float16)((a1.x - sm) * srs * g1.x + b1.x);
      h[5] = (_Float16)((a1.y - sm) * srs * g1.y + b1.y);
      h[6] = (_Float16)((a1.z - sm) * srs * g1.z + b1.z);
      h[7] = (_Float16)((a1.w - sm) * srs * g1.w + b1.w);
      *(half8*)&xh[ra][ca + j * 8] = h;
    }
  }
  __syncthreads();

  // phase 1: qkv -> qk LDS. wave w covers cols [w*144, w*144+144) (9 tiles)
  for (int nt = 0; nt < 9; ++nt) {
    const int nc = w * 144 + nt * 16;
    half8 bf[6];
    const _Float16* wp = wqkv + (size_t)(nc + ln16) * 192 + quad * 8;
    #pragma unroll
    for (int k = 0; k < 6; ++k) bf[k] = *(const half8*)(wp + k * 32);
    floatx4 a0v = {}, a1v = {};
    #pragma unroll
    for (int k = 0; k < 6; ++k) {
      half8 f0 = *(const half8*)&xh[ln16][k * 32 + quad * 8];
      half8 f1 = *(const half8*)&xh[16 + ln16][k * 32 + quad * 8];
      a0v = __builtin_amdgcn_mfma_f32_16x16x32_f16(f0, bf[k], a0v, 0, 0, 0);
      a1v = __builtin_amdgcn_mfma_f32_16x16x32_f16(f1, bf[k], a1v, 0, 0, 0);
    }
    const float bv = bqkv[nc + ln16];
    #pragma unroll
    for (int r = 0; r < 4; ++r) {
      qk[quad * 4 + r][nc + ln16]      = (_Float16)(a0v[r] + bv);
      qk[16 + quad * 4 + r][nc + ln16] = (_Float16)(a1v[r] + bv);
    }
  }
  __syncthreads();

  // phase 2: attention. wave w handles samples 2w, 2w+1 (rows 4sg..4sg+3).
  #pragma unroll
  for (int s2 = 0; s2 < 2; ++s2) {
    const int sg = w * 2 + s2;
    const int h = lane >> 4, i = (lane >> 2) & 3, j = lane & 3;
    const _Float16* qp = &qk[4 * sg + i][h * 48];
    const _Float16* kp = &qk[4 * sg + j][192 + h * 48];
    float s = 0.f;
    #pragma unroll
    for (int d = 0; d < 6; ++d) {
      half8 qv = *(const half8*)(qp + d * 8);
      half8 kv = *(const half8*)(kp + d * 8);
      #pragma unroll
      for (int e = 0; e < 8; ++e) s += (float)qv[e] * (float)kv[e];
    }
    s *= 0.14433756729740643f;  // 1/sqrt(48)
    float mx = fmaxf(s, __shfl_xor(s, 1));
    mx = fmaxf(mx, __shfl_xor(mx, 2));
    float e = expf(s - mx);
    float sum = e + __shfl_xor(e, 1);
    sum += __shfl_xor(sum, 2);
    sp[sg][h][i][j] = e / sum;   // wave-local; same wave reads below
  }
  #pragma unroll
  for (int s2 = 0; s2 < 2; ++s2) {
    const int sg = w * 2 + s2;
    #pragma unroll
    for (int ii = 0; ii < 4; ++ii) {
      #pragma unroll
      for (int cc = 0; cc < 3; ++cc) {
        const int c = lane + cc * 64;
        const int hh = c / 48;
        float a = 0.f;
        #pragma unroll
        for (int jj = 0; jj < 4; ++jj)
          a += sp[sg][hh][ii][jj] * (float)qk[4 * sg + jj][384 + c];
        xh[4 * sg + ii][c] = (_Float16)a;   // o overwrites LN1 tile (reads done)
      }
    }
  }
  __syncthreads();

  // phase 3: attn_out GEMM. wave w cols [w*48, w*48+48).
  float* outs = (float*)&qk[0][0];   // 32*192*4 = 24576 B <= 37376 B
  #pragma unroll
  for (int nt = 0; nt < 3; ++nt) {
    const int nc = w * 48 + nt * 16;
    half8 bf[6];
    const _Float16* wp = wao + (size_t)(nc + ln16) * 192 + quad * 8;
    #pragma unroll
    for (int k = 0; k < 6; ++k) bf[k] = *(const half8*)(wp + k * 32);
    floatx4 a0v = {}, a1v = {};
    #pragma unroll
    for (int k = 0; k < 6; ++k) {
      half8 f0 = *(const half8*)&xh[ln16][k * 32 + quad * 8];
      half8 f1 = *(const half8*)&xh[16 + ln16][k * 32 + quad * 8];
      a0v = __builtin_amdgcn_mfma_f32_16x16x32_f16(f0, bf[k], a0v, 0, 0, 0);
      a1v = __builtin_amdgcn_mfma_f32_16x16x32_f16(f1, bf[k], a1v, 0, 0, 0);
    }
    const float bv = bao[nc + ln16];
    #pragma unroll
    for (int r = 0; r < 4; ++r) {
      outs[(quad * 4 + r) * 192 + nc + ln16]      = a0v[r] + bv;
      outs[(16 + quad * 4 + r) * 192 + nc + ln16] = a1v[r] + bv;
    }
  }
  __syncthreads();

  // phase 4: coalesced residual add + write + LN2 stats (8 threads per row)
  {
    const int fbase = tid * 6;      // 1536 float4 total
    const int row = tid >> 3;
    float* xg = x + (size_t)m0 * 192;
    float s = 0.f, q = 0.f;
    #pragma unroll
    for (int j = 0; j < 6; ++j) {
      float4 v = ((const float4*)outs)[fbase + j];
      float4 rr = *(const float4*)(xg + (fbase + j) * 4);
      v.x += rr.x; v.y += rr.y; v.z += rr.z; v.w += rr.w;
      s += v.x + v.y + v.z + v.w;
      q += v.x * v.x + v.y * v.y + v.z * v.z + v.w * v.w;
      *(float4*)(xg + (fbase + j) * 4) = v;
    }
    s += __shfl_xor(s, 1); s += __shfl_xor(s, 2); s += __shfl_xor(s, 4);
    q += __shfl_xor(q, 1); q += __shfl_xor(q, 2); q += __shfl_xor(q, 4);
    if ((tid & 7) == 0) {
      float mean = s * (1.f / 192.f);
      stD[2 * (m0 + row)] = mean;
      stD[2 * (m0 + row) + 1] = rsqrtf(q * (1.f / 192.f) - mean * mean + 1e-5f);
    }
  }
}

// ---------------------------------------------------------------------------
// Fused FF block (per layer): x += ff2(GELU(ff1(LN2(x))))
// BM=64. FF intermediate (768) computed in two 384-col halves held in LDS;
// ff2 accumulates across halves in registers. Writes next-LN1 stats.
// ---------------------------------------------------------------------------
__global__ __launch_bounds__(256) void layer_ff_kernel(
    float* __restrict__ x, const _Float16* __restrict__ wff1,
    const float* __restrict__ bff1, const _Float16* __restrict__ wff2,
    const float* __restrict__ bff2, const float* __restrict__ ln2g,
    const float* __restrict__ ln2b_, float* __restrict__ stD) {
  __shared__ __align__(16) _Float16 xh2[64][200];   // LN2(x)
  __shared__ __align__(16) _Float16 ffh[64][392];   // FF half, then fp32 out stage
  const int tid = threadIdx.x;
  const int m0 = blockIdx.x * 64;
  const int w = tid >> 6, lane = tid & 63;
  const int ln16 = lane & 15, quad = lane >> 4;

  // phase 0: LN2(x) -> xh2 (4 threads per row, 48 floats each)
  {
    const int ra = tid >> 2, ca = (tid & 3) * 48;
    const float sm = stD[2 * (m0 + ra)], srs = stD[2 * (m0 + ra) + 1];
    const float* Ar = x + (size_t)(m0 + ra) * 192 + ca;
    #pragma unroll
    for (int j = 0; j < 6; ++j) {
      float4 a0 = *(const float4*)(Ar + j * 8);
      float4 a1 = *(const float4*)(Ar + j * 8 + 4);
      float4 g0 = *(const float4*)(ln2g + ca + j * 8);
      float4 g1 = *(const float4*)(ln2g + ca + j * 8 + 4);
      float4 b0 = *(const float4*)(ln2b_ + ca + j * 8);
      float4 b1 = *(const float4*)(ln2b_ + ca + j * 8 + 4);
      half8 h;
      h[0] = (_Float16)((a0.x - sm) * srs * g0.x + b0.x);
      h[1] = (_Float16)((a0.y - sm) * srs * g0.y + b0.y);
      h[2] = (_Float16)((a0.z - sm) * srs * g0.z + b0.z);
      h[3] = (_Float16)((a0.w - sm) * srs * g0.w + b0.w);
      h[4] = (_Float16)((a1.x - sm) * srs * g1.x + b1.x);
      h[5] = (_Float16)((a1.y - sm) * srs * g1.y + b1.y);
      h[6] = (_Float16)((a1.z - sm) * srs * g1.z + b1.z);
      h[7] = (_Float16)((a1.w - sm) * srs * g1.w + b1.w);
      *(half8*)&xh2[ra][ca + j * 8] = h;
    }
  }
  __syncthreads();

  floatx4 acc2[4][3] = {};   // ff2 accumulators, persist across halves
  for (int half = 0; half < 2; ++half) {
    // f1: FF[:, half*384 .. +384) -> ffh. wave w: 96 local cols (6 tiles).
    #pragma unroll
    for (int nt = 0; nt < 6; ++nt) {
      const int ng = half * 384 + w * 96 + nt * 16;   // global ff col
      const int nl = w * 96 + nt * 16;                // local col in ffh
      half8 bf[6];
      const _Float16* wp = wff1 + (size_t)(ng + ln16) * 192 + quad * 8;
      #pragma unroll
      for (int k = 0; k < 6; ++k) bf[k] = *(const half8*)(wp + k * 32);
      floatx4 a4[4] = {};
      #pragma unroll
      for (int k = 0; k < 6; ++k) {
        #pragma unroll
        for (int mt = 0; mt < 4; ++mt) {
          half8 af = *(const half8*)&xh2[mt * 16 + ln16][k * 32 + quad * 8];
          a4[mt] = __builtin_amdgcn_mfma_f32_16x16x32_f16(af, bf[k], a4[mt], 0, 0, 0);
        }
      }
      const float bv = bff1[ng + ln16];
      #pragma unroll
      for (int mt = 0; mt < 4; ++mt)
        #pragma unroll
        for (int r = 0; r < 4; ++r)
          ffh[mt * 16 + quad * 4 + r][nl + ln16] = (_Float16)gelu_f(a4[mt][r] + bv);
    }
    __syncthreads();
    // f2 partial: acc2 += FF_half @ wff2[:, half*384..+384)^T slice
    for (int k12 = 0; k12 < 12; ++k12) {
      half8 af[4];
      #pragma unroll
      for (int mt = 0; mt < 4; ++mt)
        af[mt] = *(const half8*)&ffh[mt * 16 + ln16][k12 * 32 + quad * 8];
      #pragma unroll
      for (int nt = 0; nt < 3; ++nt) {
        const int nc = w * 48 + nt * 16;
        half8 bf = *(const half8*)(wff2 + (size_t)(nc + ln16) * 768 +
                                   half * 384 + k12 * 32 + quad * 8);
        #pragma unroll
        for (int mt = 0; mt < 4; ++mt)
          acc2[mt][nt] = __builtin_amdgcn_mfma_f32_16x16x32_f16(
              af[mt], bf, acc2[mt][nt], 0, 0, 0);
      }
    }
    __syncthreads();   // ffh reads done before overwrite / out staging
  }

  // stage fp32 result (bias added) into ffh region
  float* outs = (float*)&ffh[0][0];   // 64*192*4 = 49152 <= 50176
  #pragma unroll
  for (int nt = 0; nt < 3; ++nt) {
    const int nc = w * 48 + nt * 16;
    const float bv = bff2[nc + ln16];
    #pragma unroll
    for (int mt = 0; mt < 4; ++mt)
      #pragma unroll
      for (int r = 0; r < 4; ++r)
        outs[(mt * 16 + quad * 4 + r) * 192 + nc + ln16] = acc2[mt][nt][r] + bv;
  }
  __syncthreads();

  // coalesced residual add + write + next-layer LN1 stats (4 threads/row)
  {
    const int fbase = tid * 12;     // 3072 float4 total
    const int row = tid >> 2;
    float* xg = x + (size_t)m0 * 192;
    float s = 0.f, q = 0.f;
    #pragma unroll
    for (int j = 0; j < 12; ++j) {
      float4 v = ((const float4*)outs)[fbase + j];
      float4 rr = *(const float4*)(xg + (fbase + j) * 4);
      v.x += rr.x; v.y += rr.y; v.z += rr.z; v.w += rr.w;
      s += v.x + v.y + v.z + v.w;
      q += v.x * v.x + v.y * v.y + v.z * v.z + v.w * v.w;
      *(float4*)(xg + (fbase + j) * 4) = v;
    }
    s += __shfl_xor(s, 1); s += __shfl_xor(s, 2);
    q += __shfl_xor(q, 1); q += __shfl_xor(q, 2);
    if ((tid & 3) == 0) {
      float mean = s * (1.f / 192.f);
      stD[2 * (m0 + row)] = mean;
      stD[2 * (m0 + row) + 1] = rsqrtf(q * (1.f / 192.f) - mean * mean + 1e-5f);
    }
  }
}

// ---------------------------------------------------------------------------
// fp32 GEMM (head only): C[M,N] = epi(A[M,K] @ W[N,K]^T + bias)
// ---------------------------------------------------------------------------
template <int EPI>
__global__ __launch_bounds__(256) void gemm_f32(
    const float* __restrict__ A, const float* __restrict__ W,
    const float* __restrict__ bias, float* __restrict__ C,
    int M, int N, int K) {
  __shared__ float As[16][68];
  __shared__ float Bs[16][68];
  const int tid = threadIdx.x;
  const int m0 = blockIdx.x * 64;
  const int n0 = blockIdx.y * 64;
  const int tx = tid & 15, ty = tid >> 4;
  const int lr = tid >> 2;
  const int lk = (tid & 3) << 2;
  float acc[4][4] = {};
  const float* Arow = A + (size_t)(m0 + lr) * K;
  const float* Wrow = W + (size_t)(n0 + lr) * K;
  for (int k0 = 0; k0 < K; k0 += 16) {
    float4 av = *(const float4*)(Arow + k0 + lk);
    float4 wv = *(const float4*)(Wrow + k0 + lk);
    __syncthreads();
    As[lk + 0][lr] = av.x; As[lk + 1][lr] = av.y;
    As[lk + 2][lr] = av.z; As[lk + 3][lr] = av.w;
    Bs[lk + 0][lr] = wv.x; Bs[lk + 1][lr] = wv.y;
    Bs[lk + 2][lr] = wv.z; Bs[lk + 3][lr] = wv.w;
    __syncthreads();
    #pragma unroll
    for (int kk = 0; kk < 16; ++kk) {
      float4 a = *(const float4*)&As[kk][ty * 4];
      float4 b = *(const float4*)&Bs[kk][tx * 4];
      acc[0][0] += a.x * b.x; acc[0][1] += a.x * b.y; acc[0][2] += a.x * b.z; acc[0][3] += a.x * b.w;
      acc[1][0] += a.y * b.x; acc[1][1] += a.y * b.y; acc[1][2] += a.y * b.z; acc[1][3] += a.y * b.w;
      acc[2][0] += a.z * b.x; acc[2][1] += a.z * b.y; acc[2][2] += a.z * b.z; acc[2][3] += a.z * b.w;
      acc[3][0] += a.w * b.x; acc[3][1] += a.w * b.y; acc[3][2] += a.w * b.z; acc[3][3] += a.w * b.w;
    }
  }
  float4 bv = *(const float4*)(bias + n0 + tx * 4);
  #pragma unroll
  for (int i = 0; i < 4; ++i) {
    int m = m0 + ty * 4 + i;
    float v0 = acc[i][0] + bv.x, v1 = acc[i][1] + bv.y;
    float v2 = acc[i][2] + bv.z, v3 = acc[i][3] + bv.w;
    if constexpr (EPI == 1) {
      v0 = gelu_f(v0); v1 = gelu_f(v1); v2 = gelu_f(v2); v3 = gelu_f(v3);
    }
    float4 ov; ov.x = v0; ov.y = v1; ov.z = v2; ov.w = v3;
    *(float4*)(C + (size_t)m * N + n0 + tx * 4) = ov;
  }
}

// ---------------------------------------------------------------------------
// mean-pool over S=4 + head LN (one wave per sample)
// ---------------------------------------------------------------------------
__global__ __launch_bounds__(256) void pool_ln_kernel(const float* __restrict__ x,
                                                      const float* __restrict__ g,
                                                      const float* __restrict__ b,
                                                      float* __restrict__ hout) {
  int bi = blockIdx.x * 4 + (threadIdx.x >> 6);
  int lane = threadIdx.x & 63;
  const float* row = x + (size_t)bi * 4 * D_;
  float vals[3];
  float sum = 0.f;
  #pragma unroll
  for (int cc = 0; cc < 3; ++cc) {
    int d = lane + cc * 64;
    float v = 0.25f * (row[d] + row[D_ + d] + row[2 * D_ + d] + row[3 * D_ + d]);
    vals[cc] = v; sum += v;
  }
  #pragma unroll
  for (int off = 1; off < 64; off <<= 1) sum += __shfl_xor(sum, off);
  float mean = sum / (float)D_;
  float vs = 0.f;
  #pragma unroll
  for (int cc = 0; cc < 3; ++cc) { float d0 = vals[cc] - mean; vs += d0 * d0; }
  #pragma unroll
  for (int off = 1; off < 64; off <<= 1) vs += __shfl_xor(vs, off);
  float rstd = rsqrtf(vs / (float)D_ + 1e-5f);
  #pragma unroll
  for (int cc = 0; cc < 3; ++cc) {
    int d = lane + cc * 64;
    hout[(size_t)bi * D_ + d] = (vals[cc] - mean) * rstd * g[d] + b[d];
  }
}

// ---------------------------------------------------------------------------
// final: out[b] = h2[b,:64] . h3_w + h3_b  (one wave per sample)
// ---------------------------------------------------------------------------
__global__ __launch_bounds__(256) void head_final_kernel(const float* __restrict__ h2,
                                                         const float* __restrict__ w,
                                                         const float* __restrict__ b,
                                                         float* __restrict__ out) {
  int bi = blockIdx.x * 4 + (threadIdx.x >> 6);
  int lane = threadIdx.x & 63;
  float v = h2[(size_t)bi * 64 + lane] * w[lane];
  #pragma unroll
  for (int off = 1; off < 64; off <<= 1) v += __shfl_xor(v, off);
  if (lane == 0) out[bi] = v + b[0];
}

// ---------------------------------------------------------------------------
extern "C" void kernel_launch(void* const* d_in, const int* in_sizes, int n_in,
                              void* d_out, int out_size, void* d_ws, size_t ws_size,
                              hipStream_t stream) {
  (void)in_sizes; (void)n_in; (void)out_size; (void)ws_size;
  const float* emb       = (const float*)d_in[0];
  const float* in_ln_w   = (const float*)d_in[1];
  const float* in_ln_b   = (const float*)d_in[2];
  const float* in_proj_w = (const float*)d_in[3];
  const float* in_proj_b = (const float*)d_in[4];
  const float* qkv_w     = (const float*)d_in[5];
  const float* qkv_b     = (const float*)d_in[6];
  const float* aow       = (const float*)d_in[7];
  const float* aob       = (const float*)d_in[8];
  const float* ln1w      = (const float*)d_in[9];
  const float* ln1b      = (const float*)d_in[10];
  const float* ln2w      = (const float*)d_in[11];
  const float* ln2b      = (const float*)d_in[12];
  const float* ff1w      = (const float*)d_in[13];
  const float* ff1b      = (const float*)d_in[14];
  const float* ff2w      = (const float*)d_in[15];
  const float* ff2b      = (const float*)d_in[16];
  const float* hlnw      = (const float*)d_in[17];
  const float* hlnb      = (const float*)d_in[18];
  const float* h1w       = (const float*)d_in[19];
  const float* h1b       = (const float*)d_in[20];
  const float* h2w       = (const float*)d_in[21];
  const float* h2b       = (const float*)d_in[22];
  const float* h3w       = (const float*)d_in[23];
  const float* h3b       = (const float*)d_in[24];
  float* out = (float*)d_out;

  float* ws = (float*)d_ws;
  size_t off = 0;
  float* x   = ws + off; off += (size_t)MTOK * D_;   // fp32 residual stream
  float* stD = ws + off; off += (size_t)MTOK * 2;    // per-token LN stats
  float* hp  = ws + off; off += (size_t)B_ * D_;
  float* h1  = ws + off; off += (size_t)B_ * 256;
  float* h2  = ws + off; off += (size_t)B_ * 64;
  // fp16 weight pack region
  _Float16* wh = (_Float16*)(ws + off);
  _Float16* w_inproj = wh;                       // 192*1152        = 221184
  _Float16* w_qkv    = w_inproj + 221184;        // 2*576*192       = 221184
  _Float16* w_ao     = w_qkv    + 221184;        // 2*192*192       =  73728
  _Float16* w_ff1    = w_ao     + 73728;         // 2*768*192       = 294912
  _Float16* w_ff2    = w_ff1    + 294912;        // 2*192*768       = 294912

  cvt_f16_kernel<<<221184 / 2048, 256, 0, stream>>>(in_proj_w, w_inproj);
  cvt_f16_kernel<<<221184 / 2048, 256, 0, stream>>>(qkv_w, w_qkv);
  cvt_f16_kernel<<<73728  / 2048, 256, 0, stream>>>(aow, w_ao);
  cvt_f16_kernel<<<294912 / 2048, 256, 0, stream>>>(ff1w, w_ff1);
  cvt_f16_kernel<<<294912 / 2048, 256, 0, stream>>>(ff2w, w_ff2);

  inproj_kernel<<<MTOK / 64, 256, 0, stream>>>(
      emb, w_inproj, in_proj_b, in_ln_w, in_ln_b, x, stD);

  for (int i = 0; i < NL_; ++i) {
    layer_attn_kernel<<<MTOK / 32, 256, 0, stream>>>(
        x, w_qkv + (size_t)i * 110592, qkv_b + (size_t)i * 576,
        w_ao + (size_t)i * 36864, aob + (size_t)i * 192,
        ln1w + (size_t)i * 192, ln1b + (size_t)i * 192, stD);
    layer_ff_kernel<<<MTOK / 64, 256, 0, stream>>>(
        x, w_ff1 + (size_t)i * 147456, ff1b + (size_t)i * 768,
        w_ff2 + (size_t)i * 147456, ff2b + (size_t)i * 192,
        ln2w + (size_t)i * 192, ln2b + (size_t)i * 192, stD);
  }

  pool_ln_kernel<<<B_ / 4, 256, 0, stream>>>(x, hlnw, hlnb, hp);
  gemm_f32<1><<<dim3(B_ / 64, 256 / 64), 256, 0, stream>>>(hp, h1w, h1b, h1, B_, 256, D_);
  gemm_f32<1><<<dim3(B_ / 64, 64 / 64), 256, 0, stream>>>(h1, h2w, h2b, h2, B_, 64, 256);
  head_final_kernel<<<B_ / 4, 256, 0, stream>>>(h2, h3w, h3b, out);
}